// Round 18
// baseline (92.113 us; speedup 1.0000x reference)
//
#include <hip/hip_runtime.h>
#include <math.h>

typedef float f32x4 __attribute__((ext_vector_type(4)));
typedef __bf16 bf16x8 __attribute__((ext_vector_type(8)));
typedef __bf16 bf16x4 __attribute__((ext_vector_type(4)));

// ---------------------------------------------------------------------------
// JAX threefry2x32 (exact port) + dropout mask replication.
// ---------------------------------------------------------------------------
struct u2 { unsigned a, b; };

__host__ __device__ constexpr u2 threefry_ce(unsigned k0, unsigned k1,
                                             unsigned c0, unsigned c1) {
  unsigned ks2 = k0 ^ k1 ^ 0x1BD11BDAu;
  unsigned x0 = c0 + k0, x1 = c1 + k1;
#define ROTL(v, n) (((v) << (n)) | ((v) >> (32 - (n))))
#define R4(a, b, c, d)                                   \
  { x0 += x1; x1 = ROTL(x1, a); x1 ^= x0;                \
    x0 += x1; x1 = ROTL(x1, b); x1 ^= x0;                \
    x0 += x1; x1 = ROTL(x1, c); x1 ^= x0;                \
    x0 += x1; x1 = ROTL(x1, d); x1 ^= x0; }
  R4(13, 15, 26, 6);  x0 += k1;  x1 += ks2 + 1u;
  R4(17, 29, 16, 24); x0 += ks2; x1 += k0 + 2u;
  R4(13, 15, 26, 6);  x0 += k0;  x1 += k1 + 3u;
  R4(17, 29, 16, 24); x0 += k1;  x1 += ks2 + 4u;
  R4(13, 15, 26, 6);  x0 += ks2; x1 += k0 + 5u;
  return u2{x0, x1};
#undef R4
#undef ROTL
}

constexpr u2 DK0 = threefry_ce(0u, 7u, 0u, 0u);
constexpr u2 DK1 = threefry_ce(0u, 7u, 0u, 1u);

__device__ __forceinline__ float dropout_scale(int layer, unsigned i) {
  unsigned k0 = layer ? DK1.a : DK0.a;
  unsigned k1 = layer ? DK1.b : DK0.b;
  unsigned ks2 = k0 ^ k1 ^ 0x1BD11BDAu;
  unsigned x0 = 0u + k0, x1 = i + k1;
#define ROTL(v, n) (((v) << (n)) | ((v) >> (32 - (n))))
#define R4(a, b, c, d)                                   \
  { x0 += x1; x1 = ROTL(x1, a); x1 ^= x0;                \
    x0 += x1; x1 = ROTL(x1, b); x1 ^= x0;                \
    x0 += x1; x1 = ROTL(x1, c); x1 ^= x0;                \
    x0 += x1; x1 = ROTL(x1, d); x1 ^= x0; }
  R4(13, 15, 26, 6);  x0 += k1;  x1 += ks2 + 1u;
  R4(17, 29, 16, 24); x0 += ks2; x1 += k0 + 2u;
  R4(13, 15, 26, 6);  x0 += k0;  x1 += k1 + 3u;
  R4(17, 29, 16, 24); x0 += k1;  x1 += ks2 + 4u;
  R4(13, 15, 26, 6);  x0 += ks2; x1 += k0 + 5u;
#undef R4
#undef ROTL
  unsigned bits = x0 ^ x1;
  return (bits & 0x80000000u) ? 0.0f : 2.0f;
}

__device__ __forceinline__ float sigmoidf(float x) {
  return 1.0f / (1.0f + expf(-x));
}

// prod_{t<64}(1-p) < 1e-13 => alignments at t>=64 bounded by ~1e-3 of output
// threshold (telescoping sum x 1e10 clip amplification) -> skippable.
#define CP_CUTOFF 64
#define CP_THRESH 1e-13f

// ---------------------------------------------------------------------------
// 1) Prenet (0..127, x-slice -> rnn_bf) + WkT prep (128..191) +
//    h1->bf16 (192..255) + h2->bf16 (256..319).
// ---------------------------------------------------------------------------
__global__ __launch_bounds__(256) void prenet_kernel(
    const float* __restrict__ mels, const float* __restrict__ W1,
    const float* __restrict__ b1, const float* __restrict__ W2,
    const float* __restrict__ b2, const float* __restrict__ Wq,
    const float* __restrict__ Wk, __bf16* __restrict__ WkT,
    const float* __restrict__ h1, __bf16* __restrict__ h1bf,
    const float* __restrict__ h2, __bf16* __restrict__ h2bf,
    __bf16* __restrict__ rnn_bf, float* __restrict__ q_out) {
  int blk = blockIdx.x;
  int j = threadIdx.x;
  if (blk >= 256) {  // h2 -> bf16
    int base = (blk - 256) * 2048 + j * 8;
    float4 v0 = *reinterpret_cast<const float4*>(&h2[base]);
    float4 v1 = *reinterpret_cast<const float4*>(&h2[base + 4]);
    bf16x8 w;
    w[0] = (__bf16)v0.x; w[1] = (__bf16)v0.y; w[2] = (__bf16)v0.z; w[3] = (__bf16)v0.w;
    w[4] = (__bf16)v1.x; w[5] = (__bf16)v1.y; w[6] = (__bf16)v1.z; w[7] = (__bf16)v1.w;
    *reinterpret_cast<bf16x8*>(&h2bf[base]) = w;
    return;
  }
  if (blk >= 192) {  // h1 -> bf16
    int base = (blk - 192) * 2048 + j * 8;
    float4 v0 = *reinterpret_cast<const float4*>(&h1[base]);
    float4 v1 = *reinterpret_cast<const float4*>(&h1[base + 4]);
    bf16x8 w;
    w[0] = (__bf16)v0.x; w[1] = (__bf16)v0.y; w[2] = (__bf16)v0.z; w[3] = (__bf16)v0.w;
    w[4] = (__bf16)v1.x; w[5] = (__bf16)v1.y; w[6] = (__bf16)v1.z; w[7] = (__bf16)v1.w;
    *reinterpret_cast<bf16x8*>(&h1bf[base]) = w;
    return;
  }
  if (blk >= 128) {  // WkT prep
    int gid = (blk - 128) * 256 + j;
    int a = gid & 127;
    int k4 = (gid >> 7) * 4;
    bf16x4 w;
    for (int i = 0; i < 4; ++i) w[i] = (__bf16)Wk[(size_t)(k4 + i) * 128 + a];
    *reinterpret_cast<bf16x4*>(&WkT[(size_t)a * 512 + k4]) = w;
    return;
  }
  int b = blk;
  __shared__ float mel_s[80];
  __shared__ float x1_s[256];
  __shared__ float x2_s[256];
  if (j < 80) mel_s[j] = mels[b * 80 + j];
  __syncthreads();
  float s = b1[j];
  for (int m = 0; m < 80; ++m) s = fmaf(mel_s[m], W1[m * 256 + j], s);
  s = fmaxf(s, 0.0f) * dropout_scale(0, (unsigned)(b * 256 + j));
  x1_s[j] = s;
  __syncthreads();
  float s2 = b2[j];
  for (int m = 0; m < 256; ++m) s2 = fmaf(x1_s[m], W2[m * 256 + j], s2);
  s2 = fmaxf(s2, 0.0f) * dropout_scale(1, (unsigned)(b * 256 + j));
  x2_s[j] = s2;
  rnn_bf[(size_t)b * 768 + j] = (__bf16)s2;
  __syncthreads();
  if (j < 128) {
    float sq = 0.0f;
    for (int m = 0; m < 256; ++m) sq = fmaf(x2_s[m], Wq[m * 128 + j], sq);
    q_out[b * 128 + j] = sq;
  }
}

// ---------------------------------------------------------------------------
// 2a) score for t<64: 16-t tiles, grid (4,128). B-frags from global.
// ---------------------------------------------------------------------------
__global__ __launch_bounds__(256) void score16_kernel(
    const float* __restrict__ enc, const __bf16* __restrict__ WkT,
    const float* __restrict__ bk, const float* __restrict__ q,
    const float* __restrict__ va_g, const float* __restrict__ bscore,
    float* __restrict__ score) {
  int b = blockIdx.y;
  int t0 = blockIdx.x * 16;
  int tid = threadIdx.x;
  int lane = tid & 63, wid = tid >> 6;
  __shared__ __align__(16) __bf16 Eb[16 * 64];
  __shared__ float red[16][4];

  f32x4 acc[2];
#pragma unroll
  for (int j = 0; j < 2; ++j) acc[j] = (f32x4){0.f, 0.f, 0.f, 0.f};

  float qv[2], vav[2];
  int an[2];
#pragma unroll
  for (int j = 0; j < 2; ++j) {
    int a = wid * 32 + j * 16 + (lane & 15);
    an[j] = a;
    qv[j] = q[b * 128 + a] + bk[a];
    vav[j] = va_g[a];
  }
  int er = tid >> 4, ek4 = (tid & 15) * 4;
  int koct = (lane >> 4) * 8;
  int tl = lane & 15;

  for (int k0 = 0; k0 < 512; k0 += 64) {
    __syncthreads();
    {
      const float4 v = *reinterpret_cast<const float4*>(
          &enc[((size_t)(b * 512 + t0 + er)) * 512 + k0 + ek4]);
      bf16x4 w;
      w[0] = (__bf16)v.x; w[1] = (__bf16)v.y;
      w[2] = (__bf16)v.z; w[3] = (__bf16)v.w;
      *reinterpret_cast<bf16x4*>(&Eb[er * 64 + (ek4 ^ ((er & 7) << 3))]) = w;
    }
    __syncthreads();
#pragma unroll
    for (int kk = 0; kk < 64; kk += 32) {
      int kl = kk + koct;
      bf16x8 af = *reinterpret_cast<const bf16x8*>(
          &Eb[tl * 64 + (kl ^ ((tl & 7) << 3))]);
      bf16x8 bfr[2];
#pragma unroll
      for (int j = 0; j < 2; ++j)
        bfr[j] = *reinterpret_cast<const bf16x8*>(
            &WkT[(size_t)an[j] * 512 + k0 + kl]);
#pragma unroll
      for (int j = 0; j < 2; ++j)
        acc[j] = __builtin_amdgcn_mfma_f32_16x16x32_bf16(af, bfr[j], acc[j], 0, 0, 0);
    }
  }

#pragma unroll
  for (int r = 0; r < 4; ++r) {
    float s = tanhf(qv[0] + acc[0][r]) * vav[0] +
              tanhf(qv[1] + acc[1][r]) * vav[1];
    s += __shfl_xor(s, 1, 64);
    s += __shfl_xor(s, 2, 64);
    s += __shfl_xor(s, 4, 64);
    s += __shfl_xor(s, 8, 64);
    if ((lane & 15) == 0) red[(lane >> 4) * 4 + r][wid] = s;
  }
  __syncthreads();
  if (tid < 16)
    score[b * 512 + t0 + tid] =
        red[tid][0] + red[tid][1] + red[tid][2] + red[tid][3] + bscore[0];
}

// ---------------------------------------------------------------------------
// 2b) score for t>=64 via 64-t tiles; inline cp-flag from score[b, 0:64).
// ---------------------------------------------------------------------------
__global__ __launch_bounds__(256) void score64_kernel(
    const float* __restrict__ enc, const __bf16* __restrict__ WkT,
    const float* __restrict__ bk, const float* __restrict__ q,
    const float* __restrict__ va_g, const float* __restrict__ bscore,
    float* __restrict__ score, int t_base) {
  int b = blockIdx.y;
  int tid = threadIdx.x;
  __shared__ float fl[64];
  if (tid < 64) fl[tid] = 1.0f - sigmoidf(score[b * 512 + tid]);
  __syncthreads();
  for (int off = 32; off >= 1; off >>= 1) {
    if (tid < off) fl[tid] *= fl[tid + off];
    __syncthreads();
  }
  if (fl[0] < CP_THRESH) return;

  int t0 = t_base + blockIdx.x * 64;
  int lane = tid & 63, wid = tid >> 6;
  int wr = wid >> 1, wc = wid & 1;
  __shared__ __align__(16) __bf16 Eb[64 * 64];
  __shared__ float red[64][2];

  f32x4 acc[2][4];
#pragma unroll
  for (int i = 0; i < 2; ++i)
#pragma unroll
    for (int j = 0; j < 4; ++j) acc[i][j] = (f32x4){0.f, 0.f, 0.f, 0.f};

  float qv[4], vav[4];
  int an[4];
#pragma unroll
  for (int j = 0; j < 4; ++j) {
    int a = wc * 64 + j * 16 + (lane & 15);
    an[j] = a;
    qv[j] = q[b * 128 + a] + bk[a];
    vav[j] = va_g[a];
  }
  int er = tid >> 4, ek4 = (tid & 15) * 4;
  int koct = (lane >> 4) * 8;

  for (int k0 = 0; k0 < 512; k0 += 64) {
    __syncthreads();
#pragma unroll
    for (int p = 0; p < 4; ++p) {
      int t = er + p * 16;
      const float4 v = *reinterpret_cast<const float4*>(
          &enc[((size_t)(b * 512 + t0 + t)) * 512 + k0 + ek4]);
      bf16x4 w;
      w[0] = (__bf16)v.x; w[1] = (__bf16)v.y;
      w[2] = (__bf16)v.z; w[3] = (__bf16)v.w;
      *reinterpret_cast<bf16x4*>(&Eb[t * 64 + (ek4 ^ ((t & 7) << 3))]) = w;
    }
    __syncthreads();
#pragma unroll
    for (int kk = 0; kk < 64; kk += 32) {
      int kl = kk + koct;
      bf16x8 af[2], bfr[4];
#pragma unroll
      for (int i = 0; i < 2; ++i) {
        int t = wr * 32 + i * 16 + (lane & 15);
        af[i] = *reinterpret_cast<const bf16x8*>(&Eb[t * 64 + (kl ^ ((t & 7) << 3))]);
      }
#pragma unroll
      for (int j = 0; j < 4; ++j)
        bfr[j] = *reinterpret_cast<const bf16x8*>(
            &WkT[(size_t)an[j] * 512 + k0 + kl]);
#pragma unroll
      for (int i = 0; i < 2; ++i)
#pragma unroll
        for (int j = 0; j < 4; ++j)
          acc[i][j] = __builtin_amdgcn_mfma_f32_16x16x32_bf16(
              af[i], bfr[j], acc[i][j], 0, 0, 0);
    }
  }

#pragma unroll
  for (int i = 0; i < 2; ++i) {
#pragma unroll
    for (int r = 0; r < 4; ++r) {
      float s = 0.0f;
#pragma unroll
      for (int j = 0; j < 4; ++j) s += tanhf(qv[j] + acc[i][j][r]) * vav[j];
      s += __shfl_xor(s, 1, 64);
      s += __shfl_xor(s, 2, 64);
      s += __shfl_xor(s, 4, 64);
      s += __shfl_xor(s, 8, 64);
      if ((lane & 15) == 0)
        red[wr * 32 + i * 16 + (lane >> 4) * 4 + r][wc] = s;
    }
  }
  __syncthreads();
  if (tid < 64)
    score[b * 512 + t0 + tid] = red[tid][0] + red[tid][1] + bscore[0];
}

// ---------------------------------------------------------------------------
// 3) Fused scan + attention context (ballot-bounded). att stored bf16.
// ---------------------------------------------------------------------------
__global__ __launch_bounds__(512) void scanatt_kernel(
    const float* __restrict__ score, const float* __restrict__ prev_align,
    const float* __restrict__ enc, float* __restrict__ align_out,
    __bf16* __restrict__ rnn_bf) {
  int b = blockIdx.x, t = threadIdx.x;
  int lane = t & 63, wv = t >> 6;
  __shared__ float wtot[8];
  __shared__ float flg_s;
  __shared__ float al_s[512];
  __shared__ int wnz[8];
  float sc0 = score[b * 512 + t];
  if (wv == 0) {
    float om = 1.0f - sigmoidf(sc0);
    for (int off = 32; off >= 1; off >>= 1) om *= __shfl_xor(om, off, 64);
    if (lane == 0) flg_s = om;
  }
  __syncthreads();
  int flg = flg_s < CP_THRESH;
  float sc = (t < CP_CUTOFF || !flg) ? sc0 : -1e30f;
  float p = sigmoidf(sc);
  float x = 1.0f - p;
#pragma unroll
  for (int off = 1; off < 64; off <<= 1) {
    float v = __shfl_up(x, off, 64);
    if (lane >= off) x *= v;
  }
  if (lane == 63) wtot[wv] = x;
  __syncthreads();
  float pre = 1.0f;
  for (int w = 0; w < wv; ++w) pre *= wtot[w];
  x *= pre;
  float xm1 = __shfl_up(x, 1, 64);
  float cp_excl = (lane == 0) ? ((wv == 0) ? 1.0f : pre) : xm1;
  float denom = fminf(fmaxf(cp_excl, 1e-10f), 1.0f);
  float r = prev_align[b * 512 + t] / denom;
  float y = r;
#pragma unroll
  for (int off = 1; off < 64; off <<= 1) {
    float v = __shfl_up(y, off, 64);
    if (lane >= off) y += v;
  }
  __syncthreads();
  if (lane == 63) wtot[wv] = y;
  __syncthreads();
  float spre = 0.0f;
  for (int w = 0; w < wv; ++w) spre += wtot[w];
  y += spre;
  float align = p * cp_excl * y;
  align_out[b * 512 + t] = align;
  al_s[t] = align;
  unsigned long long m = __ballot(align != 0.0f);
  if (lane == 0) wnz[wv] = m ? (wv * 64 + 63 - __clzll(m)) : -1;
  __syncthreads();
  int ln = -1;
#pragma unroll
  for (int w = 0; w < 8; ++w) ln = max(ln, wnz[w]);
  float acc = 0.0f;
  const float* encb = enc + (size_t)b * 512 * 512 + t;
  for (int tt = 0; tt <= ln; ++tt)
    acc = fmaf(al_s[tt], encb[(size_t)tt * 512], acc);
  rnn_bf[(size_t)b * 768 + 256 + t] = (__bf16)acc;
}

// ---------------------------------------------------------------------------
// 5) LSTM z partials via MFMA — LDS-FREE. A frags (bf16) loaded directly
//    from global (L2-hot, A <= 256KB); W frags gathered f32->bf16. No
//    barriers at all. Grid (128,4): cb = 32-col block, zp: seg/K-half.
// ---------------------------------------------------------------------------
__global__ __launch_bounds__(256) void zgemm_mfma_kernel(
    const __bf16* __restrict__ Abf0, int K0, const float* __restrict__ W0,
    const __bf16* __restrict__ Abf1, int K1, const float* __restrict__ W1,
    float* __restrict__ parts) {
  int cb = blockIdx.x;   // 0..127 (32-wide col blocks)
  int zp = blockIdx.y;   // 0..3
  int seg = zp >> 1, kh = zp & 1;
  const __bf16* A = seg ? Abf1 : Abf0;
  const float* W = seg ? W1 : W0;
  int K = seg ? K1 : K0;
  int kc = K >> 1;
  int kbeg = kh * kc, kend = kbeg + kc;
  int tid = threadIdx.x;
  int lane = tid & 63, wid = tid >> 6;
  int wr = wid >> 1, wc = wid & 1;

  f32x4 acc[4];
#pragma unroll
  for (int i = 0; i < 4; ++i) acc[i] = (f32x4){0.f, 0.f, 0.f, 0.f};

  int n_base = cb * 32 + wc * 16 + (lane & 15);
  int koct = (lane >> 4) * 8;
  size_t arow[4];
#pragma unroll
  for (int i = 0; i < 4; ++i)
    arow[i] = (size_t)(wr * 64 + i * 16 + (lane & 15)) * K;

  for (int k = kbeg; k < kend; k += 32) {
    int kl = k + koct;
    const float* wq = W + (size_t)kl * 4096 + n_base;
    bf16x8 bfr;
#pragma unroll
    for (int j = 0; j < 8; ++j) bfr[j] = (__bf16)wq[(size_t)j * 4096];
#pragma unroll
    for (int i = 0; i < 4; ++i) {
      bf16x8 af = *reinterpret_cast<const bf16x8*>(&A[arow[i] + kl]);
      acc[i] = __builtin_amdgcn_mfma_f32_16x16x32_bf16(af, bfr, acc[i], 0, 0, 0);
    }
  }

  float* outp = parts + (size_t)zp * (128 * 4096);
#pragma unroll
  for (int i = 0; i < 4; ++i)
#pragma unroll
    for (int r = 0; r < 4; ++r) {
      int row = wr * 64 + i * 16 + ((lane >> 4) << 2) + r;
      int col = cb * 32 + wc * 16 + (lane & 15);
      outp[(size_t)row * 4096 + col] = acc[i][r];
    }
}

// ---------------------------------------------------------------------------
// 6) LSTM gate (layer 1): z = sum of 4 parts + bias; also writes h1n as bf16.
// ---------------------------------------------------------------------------
__global__ __launch_bounds__(256) void gate_kernel(
    const float* __restrict__ parts, const float* __restrict__ bias,
    const float* __restrict__ c_prev, float* __restrict__ h_out,
    float* __restrict__ c_out, __bf16* __restrict__ h_bf) {
  int idx = blockIdx.x * 256 + threadIdx.x;
  int b = idx >> 10, j = idx & 1023;
  float zv[4];
  for (int g = 0; g < 4; ++g) {
    size_t off = (size_t)b * 4096 + g * 1024 + j;
    float s = bias[g * 1024 + j];
    for (int p = 0; p < 4; ++p) s += parts[(size_t)p * (128 * 4096) + off];
    zv[g] = s;
  }
  float ig = sigmoidf(zv[0]);
  float fg = sigmoidf(zv[1]);
  float gg = tanhf(zv[2]);
  float og = sigmoidf(zv[3]);
  float cn = fg * c_prev[idx] + ig * gg;
  float hn = og * tanhf(cn);
  h_out[idx] = hn;
  c_out[idx] = cn;
  h_bf[idx] = (__bf16)hn;
}

// ---------------------------------------------------------------------------
// 6b) Fused gate2 + projection: one block per b (1024 threads).
// ---------------------------------------------------------------------------
__global__ __launch_bounds__(1024) void gateproj_kernel(
    const float* __restrict__ parts, const float* __restrict__ bias,
    const float* __restrict__ c_prev, const __bf16* __restrict__ rnn_bf,
    const float* __restrict__ Wp, const float* __restrict__ bp,
    float* __restrict__ h_out, float* __restrict__ c_out,
    float* __restrict__ mel, float* __restrict__ stops) {
  int b = blockIdx.x;
  int j = threadIdx.x;
  __shared__ float row[1536];
  __shared__ float red[12][81];
  int idx = b * 1024 + j;
  float zv[4];
#pragma unroll
  for (int g = 0; g < 4; ++g) {
    size_t off = (size_t)b * 4096 + g * 1024 + j;
    float s = bias[g * 1024 + j];
#pragma unroll
    for (int p = 0; p < 4; ++p) s += parts[(size_t)p * (128 * 4096) + off];
    zv[g] = s;
  }
  float ig = sigmoidf(zv[0]);
  float fg = sigmoidf(zv[1]);
  float gg = tanhf(zv[2]);
  float og = sigmoidf(zv[3]);
  float cn = fg * c_prev[idx] + ig * gg;
  float hn = og * tanhf(cn);
  h_out[idx] = hn;
  c_out[idx] = cn;
  row[j] = hn;
  if (j < 512) row[1024 + j] = (float)rnn_bf[(size_t)b * 768 + 256 + j];
  __syncthreads();
  if (j < 972) {
    int o = j % 81, part = j / 81;
    int m0 = part * 128;
    float s = 0.0f;
    for (int m = m0; m < m0 + 128; ++m) s = fmaf(row[m], Wp[m * 81 + o], s);
    red[part][o] = s;
  }
  __syncthreads();
  if (j < 81) {
    float s = bp[j];
#pragma unroll
    for (int p = 0; p < 12; ++p) s += red[p][j];
    if (j < 80) mel[b * 80 + j] = s;
    else stops[b] = s;
  }
}

// ---------------------------------------------------------------------------
extern "C" void kernel_launch(void* const* d_in, const int* in_sizes, int n_in,
                              void* d_out, int out_size, void* d_ws,
                              size_t ws_size, hipStream_t stream) {
  const float* enc  = (const float*)d_in[0];
  const float* mels = (const float*)d_in[1];
  const float* prev = (const float*)d_in[2];
  const float* h1   = (const float*)d_in[3];
  const float* c1   = (const float*)d_in[4];
  const float* h2   = (const float*)d_in[5];
  const float* c2   = (const float*)d_in[6];
  const float* Wp1  = (const float*)d_in[7];
  const float* bp1  = (const float*)d_in[8];
  const float* Wp2  = (const float*)d_in[9];
  const float* bp2  = (const float*)d_in[10];
  const float* Wq   = (const float*)d_in[11];
  const float* Wk   = (const float*)d_in[12];
  const float* bk   = (const float*)d_in[13];
  const float* va   = (const float*)d_in[14];
  const float* bsc  = (const float*)d_in[15];
  const float* Wx1  = (const float*)d_in[16];
  const float* Wh1  = (const float*)d_in[17];
  const float* bl1  = (const float*)d_in[18];
  const float* Wx2  = (const float*)d_in[19];
  const float* Wh2  = (const float*)d_in[20];
  const float* bl2  = (const float*)d_in[21];
  const float* Wpj  = (const float*)d_in[22];
  const float* bpj  = (const float*)d_in[23];

  float* out = (float*)d_out;
  float* mel    = out;            // 128*80
  float* stops  = out + 10240;    // 128
  float* aligno = out + 10368;    // 128*512
  float* h1n    = out + 75904;    // 128*1024
  float* c1n    = out + 206976;
  float* h2n    = out + 338048;
  float* c2n    = out + 469120;

  float* ws = (float*)d_ws;
  float* q_ws   = ws;              // 16384
  float* sc_ws  = ws + 16384;      // 65536
  __bf16* rnn_bf = (__bf16*)(ws + 81920);   // 128*768 bf16 = 49152 f
  float* parts  = ws + 180224;     // 4 * 524288 = 2,097,152
  __bf16* h1bf  = (__bf16*)(ws + 2277376);  // 131072 bf16 = 65536 f
  __bf16* h2bf  = (__bf16*)(ws + 2342912);
  __bf16* h1nbf = (__bf16*)(ws + 2408448);
  // WkT (bf16, 128KB) aliases head of `parts` — consumed before zgemm runs.
  __bf16* WkT = (__bf16*)parts;

  hipLaunchKernelGGL(prenet_kernel, dim3(320), dim3(256), 0, stream,
                     mels, Wp1, bp1, Wp2, bp2, Wq, Wk, WkT,
                     h1, h1bf, h2, h2bf, rnn_bf, q_ws);
  hipLaunchKernelGGL(score16_kernel, dim3(4, 128), dim3(256), 0, stream,
                     enc, WkT, bk, q_ws, va, bsc, sc_ws);
  hipLaunchKernelGGL(score64_kernel, dim3(7, 128), dim3(256), 0, stream,
                     enc, WkT, bk, q_ws, va, bsc, sc_ws, 64);
  hipLaunchKernelGGL(scanatt_kernel, dim3(128), dim3(512), 0, stream,
                     sc_ws, prev, enc, aligno, rnn_bf);
  hipLaunchKernelGGL(zgemm_mfma_kernel, dim3(128, 4), dim3(256), 0, stream,
                     rnn_bf, 768, Wx1, h1bf, 1024, Wh1, parts);
  hipLaunchKernelGGL(gate_kernel, dim3(512), dim3(256), 0, stream,
                     parts, bl1, c1, h1n, c1n, h1nbf);
  hipLaunchKernelGGL(zgemm_mfma_kernel, dim3(128, 4), dim3(256), 0, stream,
                     h1nbf, 1024, Wx2, h2bf, 1024, Wh2, parts);
  hipLaunchKernelGGL(gateproj_kernel, dim3(128), dim3(1024), 0, stream,
                     parts, bl2, c2, rnn_bf, Wpj, bpj, h2n, c2n, mel, stops);
}

// Round 19
// 79.492 us; speedup vs baseline: 1.1588x; 1.1588x over previous
//
#include <hip/hip_runtime.h>
#include <math.h>

typedef float f32x4 __attribute__((ext_vector_type(4)));
typedef __bf16 bf16x8 __attribute__((ext_vector_type(8)));
typedef __bf16 bf16x4 __attribute__((ext_vector_type(4)));

// ---------------------------------------------------------------------------
// JAX threefry2x32 (exact port) + dropout mask replication.
// ---------------------------------------------------------------------------
struct u2 { unsigned a, b; };

__host__ __device__ constexpr u2 threefry_ce(unsigned k0, unsigned k1,
                                             unsigned c0, unsigned c1) {
  unsigned ks2 = k0 ^ k1 ^ 0x1BD11BDAu;
  unsigned x0 = c0 + k0, x1 = c1 + k1;
#define ROTL(v, n) (((v) << (n)) | ((v) >> (32 - (n))))
#define R4(a, b, c, d)                                   \
  { x0 += x1; x1 = ROTL(x1, a); x1 ^= x0;                \
    x0 += x1; x1 = ROTL(x1, b); x1 ^= x0;                \
    x0 += x1; x1 = ROTL(x1, c); x1 ^= x0;                \
    x0 += x1; x1 = ROTL(x1, d); x1 ^= x0; }
  R4(13, 15, 26, 6);  x0 += k1;  x1 += ks2 + 1u;
  R4(17, 29, 16, 24); x0 += ks2; x1 += k0 + 2u;
  R4(13, 15, 26, 6);  x0 += k0;  x1 += k1 + 3u;
  R4(17, 29, 16, 24); x0 += k1;  x1 += ks2 + 4u;
  R4(13, 15, 26, 6);  x0 += ks2; x1 += k0 + 5u;
  return u2{x0, x1};
#undef R4
#undef ROTL
}

constexpr u2 DK0 = threefry_ce(0u, 7u, 0u, 0u);
constexpr u2 DK1 = threefry_ce(0u, 7u, 0u, 1u);

__device__ __forceinline__ float dropout_scale(int layer, unsigned i) {
  unsigned k0 = layer ? DK1.a : DK0.a;
  unsigned k1 = layer ? DK1.b : DK0.b;
  unsigned ks2 = k0 ^ k1 ^ 0x1BD11BDAu;
  unsigned x0 = 0u + k0, x1 = i + k1;
#define ROTL(v, n) (((v) << (n)) | ((v) >> (32 - (n))))
#define R4(a, b, c, d)                                   \
  { x0 += x1; x1 = ROTL(x1, a); x1 ^= x0;                \
    x0 += x1; x1 = ROTL(x1, b); x1 ^= x0;                \
    x0 += x1; x1 = ROTL(x1, c); x1 ^= x0;                \
    x0 += x1; x1 = ROTL(x1, d); x1 ^= x0; }
  R4(13, 15, 26, 6);  x0 += k1;  x1 += ks2 + 1u;
  R4(17, 29, 16, 24); x0 += ks2; x1 += k0 + 2u;
  R4(13, 15, 26, 6);  x0 += k0;  x1 += k1 + 3u;
  R4(17, 29, 16, 24); x0 += k1;  x1 += ks2 + 4u;
  R4(13, 15, 26, 6);  x0 += ks2; x1 += k0 + 5u;
#undef R4
#undef ROTL
  unsigned bits = x0 ^ x1;
  return (bits & 0x80000000u) ? 0.0f : 2.0f;
}

__device__ __forceinline__ float sigmoidf(float x) {
  return 1.0f / (1.0f + expf(-x));
}

// prod_{t<64}(1-p) < 1e-13 => alignments at t>=64 bounded by ~1e-3 of output
// threshold (telescoping sum x 1e10 clip amplification) -> skippable.
#define CP_CUTOFF 64
#define CP_THRESH 1e-13f

// ---------------------------------------------------------------------------
// 1) Prenet (0..127) + WkT prep (128..191) + h1->bf16 (192..255) +
//    h2->bf16 (256..319).
// ---------------------------------------------------------------------------
__global__ __launch_bounds__(256) void prenet_kernel(
    const float* __restrict__ mels, const float* __restrict__ W1,
    const float* __restrict__ b1, const float* __restrict__ W2,
    const float* __restrict__ b2, const float* __restrict__ Wq,
    const float* __restrict__ Wk, __bf16* __restrict__ WkT,
    const float* __restrict__ h1, __bf16* __restrict__ h1bf,
    const float* __restrict__ h2, __bf16* __restrict__ h2bf,
    float* __restrict__ rnn_in, float* __restrict__ q_out) {
  int blk = blockIdx.x;
  int j = threadIdx.x;
  if (blk >= 256) {  // h2 -> bf16
    int base = (blk - 256) * 2048 + j * 8;
    float4 v0 = *reinterpret_cast<const float4*>(&h2[base]);
    float4 v1 = *reinterpret_cast<const float4*>(&h2[base + 4]);
    bf16x8 w;
    w[0] = (__bf16)v0.x; w[1] = (__bf16)v0.y; w[2] = (__bf16)v0.z; w[3] = (__bf16)v0.w;
    w[4] = (__bf16)v1.x; w[5] = (__bf16)v1.y; w[6] = (__bf16)v1.z; w[7] = (__bf16)v1.w;
    *reinterpret_cast<bf16x8*>(&h2bf[base]) = w;
    return;
  }
  if (blk >= 192) {  // h1 -> bf16
    int base = (blk - 192) * 2048 + j * 8;
    float4 v0 = *reinterpret_cast<const float4*>(&h1[base]);
    float4 v1 = *reinterpret_cast<const float4*>(&h1[base + 4]);
    bf16x8 w;
    w[0] = (__bf16)v0.x; w[1] = (__bf16)v0.y; w[2] = (__bf16)v0.z; w[3] = (__bf16)v0.w;
    w[4] = (__bf16)v1.x; w[5] = (__bf16)v1.y; w[6] = (__bf16)v1.z; w[7] = (__bf16)v1.w;
    *reinterpret_cast<bf16x8*>(&h1bf[base]) = w;
    return;
  }
  if (blk >= 128) {  // WkT prep
    int gid = (blk - 128) * 256 + j;
    int a = gid & 127;
    int k4 = (gid >> 7) * 4;
    bf16x4 w;
    for (int i = 0; i < 4; ++i) w[i] = (__bf16)Wk[(size_t)(k4 + i) * 128 + a];
    *reinterpret_cast<bf16x4*>(&WkT[(size_t)a * 512 + k4]) = w;
    return;
  }
  int b = blk;
  __shared__ float mel_s[80];
  __shared__ float x1_s[256];
  __shared__ float x2_s[256];
  if (j < 80) mel_s[j] = mels[b * 80 + j];
  __syncthreads();
  float s = b1[j];
  for (int m = 0; m < 80; ++m) s = fmaf(mel_s[m], W1[m * 256 + j], s);
  s = fmaxf(s, 0.0f) * dropout_scale(0, (unsigned)(b * 256 + j));
  x1_s[j] = s;
  __syncthreads();
  float s2 = b2[j];
  for (int m = 0; m < 256; ++m) s2 = fmaf(x1_s[m], W2[m * 256 + j], s2);
  s2 = fmaxf(s2, 0.0f) * dropout_scale(1, (unsigned)(b * 256 + j));
  x2_s[j] = s2;
  rnn_in[(size_t)b * 768 + j] = s2;
  __syncthreads();
  if (j < 128) {
    float sq = 0.0f;
    for (int m = 0; m < 256; ++m) sq = fmaf(x2_s[m], Wq[m * 128 + j], sq);
    q_out[b * 128 + j] = sq;
  }
}

// ---------------------------------------------------------------------------
// 2a) score for t<64: 16-t tiles, grid (4,128). B-frags from global.
// ---------------------------------------------------------------------------
__global__ __launch_bounds__(256) void score16_kernel(
    const float* __restrict__ enc, const __bf16* __restrict__ WkT,
    const float* __restrict__ bk, const float* __restrict__ q,
    const float* __restrict__ va_g, const float* __restrict__ bscore,
    float* __restrict__ score) {
  int b = blockIdx.y;
  int t0 = blockIdx.x * 16;
  int tid = threadIdx.x;
  int lane = tid & 63, wid = tid >> 6;
  __shared__ __align__(16) __bf16 Eb[16 * 64];
  __shared__ float red[16][4];

  f32x4 acc[2];
#pragma unroll
  for (int j = 0; j < 2; ++j) acc[j] = (f32x4){0.f, 0.f, 0.f, 0.f};

  float qv[2], vav[2];
  int an[2];
#pragma unroll
  for (int j = 0; j < 2; ++j) {
    int a = wid * 32 + j * 16 + (lane & 15);
    an[j] = a;
    qv[j] = q[b * 128 + a] + bk[a];
    vav[j] = va_g[a];
  }
  int er = tid >> 4, ek4 = (tid & 15) * 4;
  int koct = (lane >> 4) * 8;
  int tl = lane & 15;

  for (int k0 = 0; k0 < 512; k0 += 64) {
    __syncthreads();
    {
      const float4 v = *reinterpret_cast<const float4*>(
          &enc[((size_t)(b * 512 + t0 + er)) * 512 + k0 + ek4]);
      bf16x4 w;
      w[0] = (__bf16)v.x; w[1] = (__bf16)v.y;
      w[2] = (__bf16)v.z; w[3] = (__bf16)v.w;
      *reinterpret_cast<bf16x4*>(&Eb[er * 64 + (ek4 ^ ((er & 7) << 3))]) = w;
    }
    __syncthreads();
#pragma unroll
    for (int kk = 0; kk < 64; kk += 32) {
      int kl = kk + koct;
      bf16x8 af = *reinterpret_cast<const bf16x8*>(
          &Eb[tl * 64 + (kl ^ ((tl & 7) << 3))]);
      bf16x8 bfr[2];
#pragma unroll
      for (int j = 0; j < 2; ++j)
        bfr[j] = *reinterpret_cast<const bf16x8*>(
            &WkT[(size_t)an[j] * 512 + k0 + kl]);
#pragma unroll
      for (int j = 0; j < 2; ++j)
        acc[j] = __builtin_amdgcn_mfma_f32_16x16x32_bf16(af, bfr[j], acc[j], 0, 0, 0);
    }
  }

#pragma unroll
  for (int r = 0; r < 4; ++r) {
    float s = tanhf(qv[0] + acc[0][r]) * vav[0] +
              tanhf(qv[1] + acc[1][r]) * vav[1];
    s += __shfl_xor(s, 1, 64);
    s += __shfl_xor(s, 2, 64);
    s += __shfl_xor(s, 4, 64);
    s += __shfl_xor(s, 8, 64);
    if ((lane & 15) == 0) red[(lane >> 4) * 4 + r][wid] = s;
  }
  __syncthreads();
  if (tid < 16)
    score[b * 512 + t0 + tid] =
        red[tid][0] + red[tid][1] + red[tid][2] + red[tid][3] + bscore[0];
}

// ---------------------------------------------------------------------------
// 2b) score for t>=64 via 64-t tiles; inline cp-flag from score[b, 0:64).
// ---------------------------------------------------------------------------
__global__ __launch_bounds__(256) void score64_kernel(
    const float* __restrict__ enc, const __bf16* __restrict__ WkT,
    const float* __restrict__ bk, const float* __restrict__ q,
    const float* __restrict__ va_g, const float* __restrict__ bscore,
    float* __restrict__ score, int t_base) {
  int b = blockIdx.y;
  int tid = threadIdx.x;
  __shared__ float fl[64];
  if (tid < 64) fl[tid] = 1.0f - sigmoidf(score[b * 512 + tid]);
  __syncthreads();
  for (int off = 32; off >= 1; off >>= 1) {
    if (tid < off) fl[tid] *= fl[tid + off];
    __syncthreads();
  }
  if (fl[0] < CP_THRESH) return;

  int t0 = t_base + blockIdx.x * 64;
  int lane = tid & 63, wid = tid >> 6;
  int wr = wid >> 1, wc = wid & 1;
  __shared__ __align__(16) __bf16 Eb[64 * 64];
  __shared__ float red[64][2];

  f32x4 acc[2][4];
#pragma unroll
  for (int i = 0; i < 2; ++i)
#pragma unroll
    for (int j = 0; j < 4; ++j) acc[i][j] = (f32x4){0.f, 0.f, 0.f, 0.f};

  float qv[4], vav[4];
  int an[4];
#pragma unroll
  for (int j = 0; j < 4; ++j) {
    int a = wc * 64 + j * 16 + (lane & 15);
    an[j] = a;
    qv[j] = q[b * 128 + a] + bk[a];
    vav[j] = va_g[a];
  }
  int er = tid >> 4, ek4 = (tid & 15) * 4;
  int koct = (lane >> 4) * 8;

  for (int k0 = 0; k0 < 512; k0 += 64) {
    __syncthreads();
#pragma unroll
    for (int p = 0; p < 4; ++p) {
      int t = er + p * 16;
      const float4 v = *reinterpret_cast<const float4*>(
          &enc[((size_t)(b * 512 + t0 + t)) * 512 + k0 + ek4]);
      bf16x4 w;
      w[0] = (__bf16)v.x; w[1] = (__bf16)v.y;
      w[2] = (__bf16)v.z; w[3] = (__bf16)v.w;
      *reinterpret_cast<bf16x4*>(&Eb[t * 64 + (ek4 ^ ((t & 7) << 3))]) = w;
    }
    __syncthreads();
#pragma unroll
    for (int kk = 0; kk < 64; kk += 32) {
      int kl = kk + koct;
      bf16x8 af[2], bfr[4];
#pragma unroll
      for (int i = 0; i < 2; ++i) {
        int t = wr * 32 + i * 16 + (lane & 15);
        af[i] = *reinterpret_cast<const bf16x8*>(&Eb[t * 64 + (kl ^ ((t & 7) << 3))]);
      }
#pragma unroll
      for (int j = 0; j < 4; ++j)
        bfr[j] = *reinterpret_cast<const bf16x8*>(
            &WkT[(size_t)an[j] * 512 + k0 + kl]);
#pragma unroll
      for (int i = 0; i < 2; ++i)
#pragma unroll
        for (int j = 0; j < 4; ++j)
          acc[i][j] = __builtin_amdgcn_mfma_f32_16x16x32_bf16(
              af[i], bfr[j], acc[i][j], 0, 0, 0);
    }
  }

#pragma unroll
  for (int i = 0; i < 2; ++i) {
#pragma unroll
    for (int r = 0; r < 4; ++r) {
      float s = 0.0f;
#pragma unroll
      for (int j = 0; j < 4; ++j) s += tanhf(qv[j] + acc[i][j][r]) * vav[j];
      s += __shfl_xor(s, 1, 64);
      s += __shfl_xor(s, 2, 64);
      s += __shfl_xor(s, 4, 64);
      s += __shfl_xor(s, 8, 64);
      if ((lane & 15) == 0)
        red[wr * 32 + i * 16 + (lane >> 4) * 4 + r][wc] = s;
    }
  }
  __syncthreads();
  if (tid < 64)
    score[b * 512 + t0 + tid] = red[tid][0] + red[tid][1] + bscore[0];
}

// ---------------------------------------------------------------------------
// 3) Fused scan + attention context (ballot-bounded).
// ---------------------------------------------------------------------------
__global__ __launch_bounds__(512) void scanatt_kernel(
    const float* __restrict__ score, const float* __restrict__ prev_align,
    const float* __restrict__ enc, float* __restrict__ align_out,
    float* __restrict__ rnn_in) {
  int b = blockIdx.x, t = threadIdx.x;
  int lane = t & 63, wv = t >> 6;
  __shared__ float wtot[8];
  __shared__ float flg_s;
  __shared__ float al_s[512];
  __shared__ int wnz[8];
  float sc0 = score[b * 512 + t];
  if (wv == 0) {
    float om = 1.0f - sigmoidf(sc0);
    for (int off = 32; off >= 1; off >>= 1) om *= __shfl_xor(om, off, 64);
    if (lane == 0) flg_s = om;
  }
  __syncthreads();
  int flg = flg_s < CP_THRESH;
  float sc = (t < CP_CUTOFF || !flg) ? sc0 : -1e30f;
  float p = sigmoidf(sc);
  float x = 1.0f - p;
#pragma unroll
  for (int off = 1; off < 64; off <<= 1) {
    float v = __shfl_up(x, off, 64);
    if (lane >= off) x *= v;
  }
  if (lane == 63) wtot[wv] = x;
  __syncthreads();
  float pre = 1.0f;
  for (int w = 0; w < wv; ++w) pre *= wtot[w];
  x *= pre;
  float xm1 = __shfl_up(x, 1, 64);
  float cp_excl = (lane == 0) ? ((wv == 0) ? 1.0f : pre) : xm1;
  float denom = fminf(fmaxf(cp_excl, 1e-10f), 1.0f);
  float r = prev_align[b * 512 + t] / denom;
  float y = r;
#pragma unroll
  for (int off = 1; off < 64; off <<= 1) {
    float v = __shfl_up(y, off, 64);
    if (lane >= off) y += v;
  }
  __syncthreads();
  if (lane == 63) wtot[wv] = y;
  __syncthreads();
  float spre = 0.0f;
  for (int w = 0; w < wv; ++w) spre += wtot[w];
  y += spre;
  float align = p * cp_excl * y;
  align_out[b * 512 + t] = align;
  al_s[t] = align;
  unsigned long long m = __ballot(align != 0.0f);
  if (lane == 0) wnz[wv] = m ? (wv * 64 + 63 - __clzll(m)) : -1;
  __syncthreads();
  int ln = -1;
#pragma unroll
  for (int w = 0; w < 8; ++w) ln = max(ln, wnz[w]);
  float acc = 0.0f;
  const float* encb = enc + (size_t)b * 512 * 512 + t;
  for (int tt = 0; tt <= ln; ++tt)
    acc = fmaf(al_s[tt], encb[(size_t)tt * 512], acc);
  rnn_in[(size_t)b * 768 + 256 + t] = acc;
}

// ---------------------------------------------------------------------------
// 5) LSTM z partials via MFMA: grid (128,4) = 512 blocks; LDS-staged A.
// ---------------------------------------------------------------------------
__global__ __launch_bounds__(256) void zgemm_mfma_kernel(
    const float* __restrict__ A0, const __bf16* __restrict__ Abf0, int K0,
    const float* __restrict__ W0,
    const float* __restrict__ A1, const __bf16* __restrict__ Abf1, int K1,
    const float* __restrict__ W1,
    float* __restrict__ parts) {
  int cb = blockIdx.x;   // 0..127 (32-wide col blocks)
  int zp = blockIdx.y;   // 0..3
  int seg = zp >> 1, kh = zp & 1;
  const float* A = seg ? A1 : A0;
  const __bf16* Abf = seg ? Abf1 : Abf0;
  const float* W = seg ? W1 : W0;
  int K = seg ? K1 : K0;
  int kc = K >> 1;
  int kbeg = kh * kc, kend = kbeg + kc;
  int tid = threadIdx.x;
  int lane = tid & 63, wid = tid >> 6;
  int wr = wid >> 1, wc = wid & 1;
  __shared__ __align__(16) __bf16 Ab[128 * 64];

  f32x4 acc[4];
#pragma unroll
  for (int i = 0; i < 4; ++i) acc[i] = (f32x4){0.f, 0.f, 0.f, 0.f};

  int n_base = cb * 32 + wc * 16 + (lane & 15);
  int koct = (lane >> 4) * 8;

  for (int k0 = kbeg; k0 < kend; k0 += 64) {
    __syncthreads();
    if (Abf) {  // bf16 source: 16B loads, swizzle-preserving 16B stores
      int r4 = tid >> 3;         // 0..31
      int k8 = (tid & 7) * 8;    // 0..56
#pragma unroll
      for (int p = 0; p < 4; ++p) {
        int row = r4 + p * 32;
        bf16x8 v = *reinterpret_cast<const bf16x8*>(
            &Abf[(size_t)row * K + k0 + k8]);
        *reinterpret_cast<bf16x8*>(&Ab[row * 64 + (k8 ^ ((row & 7) << 3))]) = v;
      }
    } else {
      int r = tid >> 4;
      int k4 = (tid & 15) * 4;
#pragma unroll
      for (int p = 0; p < 8; ++p) {
        int row = r + p * 16;
        const float4 v = *reinterpret_cast<const float4*>(
            &A[(size_t)row * K + k0 + k4]);
        bf16x4 w;
        w[0] = (__bf16)v.x; w[1] = (__bf16)v.y;
        w[2] = (__bf16)v.z; w[3] = (__bf16)v.w;
        *reinterpret_cast<bf16x4*>(&Ab[row * 64 + (k4 ^ ((row & 7) << 3))]) = w;
      }
    }
    __syncthreads();
#pragma unroll
    for (int kk = 0; kk < 64; kk += 32) {
      const float* wq = W + (size_t)(k0 + kk + koct) * 4096 + n_base;
      bf16x8 bfr;
#pragma unroll
      for (int j = 0; j < 8; ++j) bfr[j] = (__bf16)wq[(size_t)j * 4096];
      int kl = kk + koct;
#pragma unroll
      for (int i = 0; i < 4; ++i) {
        int t = wr * 64 + i * 16 + (lane & 15);
        bf16x8 af = *reinterpret_cast<const bf16x8*>(
            &Ab[t * 64 + (kl ^ ((t & 7) << 3))]);
        acc[i] = __builtin_amdgcn_mfma_f32_16x16x32_bf16(af, bfr, acc[i], 0, 0, 0);
      }
    }
  }

  float* outp = parts + (size_t)zp * (128 * 4096);
#pragma unroll
  for (int i = 0; i < 4; ++i)
#pragma unroll
    for (int r = 0; r < 4; ++r) {
      int row = wr * 64 + i * 16 + ((lane >> 4) << 2) + r;
      int col = cb * 32 + wc * 16 + (lane & 15);
      outp[(size_t)row * 4096 + col] = acc[i][r];
    }
}

// ---------------------------------------------------------------------------
// 6) LSTM gate (layer 1): z = sum of 4 parts + bias; also writes h1n as bf16.
// ---------------------------------------------------------------------------
__global__ __launch_bounds__(256) void gate_kernel(
    const float* __restrict__ parts, const float* __restrict__ bias,
    const float* __restrict__ c_prev, float* __restrict__ h_out,
    float* __restrict__ c_out, __bf16* __restrict__ h_bf) {
  int idx = blockIdx.x * 256 + threadIdx.x;
  int b = idx >> 10, j = idx & 1023;
  float zv[4];
  for (int g = 0; g < 4; ++g) {
    size_t off = (size_t)b * 4096 + g * 1024 + j;
    float s = bias[g * 1024 + j];
    for (int p = 0; p < 4; ++p) s += parts[(size_t)p * (128 * 4096) + off];
    zv[g] = s;
  }
  float ig = sigmoidf(zv[0]);
  float fg = sigmoidf(zv[1]);
  float gg = tanhf(zv[2]);
  float og = sigmoidf(zv[3]);
  float cn = fg * c_prev[idx] + ig * gg;
  float hn = og * tanhf(cn);
  h_out[idx] = hn;
  c_out[idx] = cn;
  h_bf[idx] = (__bf16)hn;
}

// ---------------------------------------------------------------------------
// 6b) Fused gate2 + projection: one block per b (1024 threads).
// ---------------------------------------------------------------------------
__global__ __launch_bounds__(1024) void gateproj_kernel(
    const float* __restrict__ parts, const float* __restrict__ bias,
    const float* __restrict__ c_prev, const float* __restrict__ rnn_in,
    const float* __restrict__ Wp, const float* __restrict__ bp,
    float* __restrict__ h_out, float* __restrict__ c_out,
    float* __restrict__ mel, float* __restrict__ stops) {
  int b = blockIdx.x;
  int j = threadIdx.x;
  __shared__ float row[1536];
  __shared__ float red[12][81];
  int idx = b * 1024 + j;
  float zv[4];
#pragma unroll
  for (int g = 0; g < 4; ++g) {
    size_t off = (size_t)b * 4096 + g * 1024 + j;
    float s = bias[g * 1024 + j];
#pragma unroll
    for (int p = 0; p < 4; ++p) s += parts[(size_t)p * (128 * 4096) + off];
    zv[g] = s;
  }
  float ig = sigmoidf(zv[0]);
  float fg = sigmoidf(zv[1]);
  float gg = tanhf(zv[2]);
  float og = sigmoidf(zv[3]);
  float cn = fg * c_prev[idx] + ig * gg;
  float hn = og * tanhf(cn);
  h_out[idx] = hn;
  c_out[idx] = cn;
  row[j] = hn;
  if (j < 512) row[1024 + j] = rnn_in[(size_t)b * 768 + 256 + j];
  __syncthreads();
  if (j < 972) {
    int o = j % 81, part = j / 81;
    int m0 = part * 128;
    float s = 0.0f;
    for (int m = m0; m < m0 + 128; ++m) s = fmaf(row[m], Wp[m * 81 + o], s);
    red[part][o] = s;
  }
  __syncthreads();
  if (j < 81) {
    float s = bp[j];
#pragma unroll
    for (int p = 0; p < 12; ++p) s += red[p][j];
    if (j < 80) mel[b * 80 + j] = s;
    else stops[b] = s;
  }
}

// ---------------------------------------------------------------------------
extern "C" void kernel_launch(void* const* d_in, const int* in_sizes, int n_in,
                              void* d_out, int out_size, void* d_ws,
                              size_t ws_size, hipStream_t stream) {
  const float* enc  = (const float*)d_in[0];
  const float* mels = (const float*)d_in[1];
  const float* prev = (const float*)d_in[2];
  const float* h1   = (const float*)d_in[3];
  const float* c1   = (const float*)d_in[4];
  const float* h2   = (const float*)d_in[5];
  const float* c2   = (const float*)d_in[6];
  const float* Wp1  = (const float*)d_in[7];
  const float* bp1  = (const float*)d_in[8];
  const float* Wp2  = (const float*)d_in[9];
  const float* bp2  = (const float*)d_in[10];
  const float* Wq   = (const float*)d_in[11];
  const float* Wk   = (const float*)d_in[12];
  const float* bk   = (const float*)d_in[13];
  const float* va   = (const float*)d_in[14];
  const float* bsc  = (const float*)d_in[15];
  const float* Wx1  = (const float*)d_in[16];
  const float* Wh1  = (const float*)d_in[17];
  const float* bl1  = (const float*)d_in[18];
  const float* Wx2  = (const float*)d_in[19];
  const float* Wh2  = (const float*)d_in[20];
  const float* bl2  = (const float*)d_in[21];
  const float* Wpj  = (const float*)d_in[22];
  const float* bpj  = (const float*)d_in[23];

  float* out = (float*)d_out;
  float* mel    = out;            // 128*80
  float* stops  = out + 10240;    // 128
  float* aligno = out + 10368;    // 128*512
  float* h1n    = out + 75904;    // 128*1024
  float* c1n    = out + 206976;
  float* h2n    = out + 338048;
  float* c2n    = out + 469120;

  float* ws = (float*)d_ws;
  float* q_ws   = ws;              // 16384
  float* sc_ws  = ws + 16384;      // 65536
  float* rnn_in = ws + 81920;      // 98304
  float* parts  = ws + 180224;     // 4 * 524288 = 2,097,152
  __bf16* h1bf  = (__bf16*)(ws + 2277376);  // 131072 bf16 = 65536 f
  __bf16* h2bf  = (__bf16*)(ws + 2342912);
  __bf16* h1nbf = (__bf16*)(ws + 2408448);
  // WkT (bf16, 128KB) aliases head of `parts` — consumed before zgemm runs.
  __bf16* WkT = (__bf16*)parts;

  hipLaunchKernelGGL(prenet_kernel, dim3(320), dim3(256), 0, stream,
                     mels, Wp1, bp1, Wp2, bp2, Wq, Wk, WkT,
                     h1, h1bf, h2, h2bf, rnn_in, q_ws);
  hipLaunchKernelGGL(score16_kernel, dim3(4, 128), dim3(256), 0, stream,
                     enc, WkT, bk, q_ws, va, bsc, sc_ws);
  hipLaunchKernelGGL(score64_kernel, dim3(7, 128), dim3(256), 0, stream,
                     enc, WkT, bk, q_ws, va, bsc, sc_ws, 64);
  hipLaunchKernelGGL(scanatt_kernel, dim3(128), dim3(512), 0, stream,
                     sc_ws, prev, enc, aligno, rnn_in);
  hipLaunchKernelGGL(zgemm_mfma_kernel, dim3(128, 4), dim3(256), 0, stream,
                     rnn_in, (const __bf16*)nullptr, 768, Wx1,
                     h1, h1bf, 1024, Wh1, parts);
  hipLaunchKernelGGL(gate_kernel, dim3(512), dim3(256), 0, stream,
                     parts, bl1, c1, h1n, c1n, h1nbf);
  hipLaunchKernelGGL(zgemm_mfma_kernel, dim3(128, 4), dim3(256), 0, stream,
                     h1n, h1nbf, 1024, Wx2,
                     h2, h2bf, 1024, Wh2, parts);
  hipLaunchKernelGGL(gateproj_kernel, dim3(128), dim3(1024), 0, stream,
                     parts, bl2, c2, rnn_in, Wpj, bpj, h2n, c2n, mel, stops);
}

// Round 20
// 77.748 us; speedup vs baseline: 1.1848x; 1.0224x over previous
//
#include <hip/hip_runtime.h>
#include <math.h>

typedef float f32x4 __attribute__((ext_vector_type(4)));
typedef __bf16 bf16x8 __attribute__((ext_vector_type(8)));
typedef __bf16 bf16x4 __attribute__((ext_vector_type(4)));

// ---------------------------------------------------------------------------
// JAX threefry2x32 (exact port) + dropout mask replication.
// ---------------------------------------------------------------------------
struct u2 { unsigned a, b; };

__host__ __device__ constexpr u2 threefry_ce(unsigned k0, unsigned k1,
                                             unsigned c0, unsigned c1) {
  unsigned ks2 = k0 ^ k1 ^ 0x1BD11BDAu;
  unsigned x0 = c0 + k0, x1 = c1 + k1;
#define ROTL(v, n) (((v) << (n)) | ((v) >> (32 - (n))))
#define R4(a, b, c, d)                                   \
  { x0 += x1; x1 = ROTL(x1, a); x1 ^= x0;                \
    x0 += x1; x1 = ROTL(x1, b); x1 ^= x0;                \
    x0 += x1; x1 = ROTL(x1, c); x1 ^= x0;                \
    x0 += x1; x1 = ROTL(x1, d); x1 ^= x0; }
  R4(13, 15, 26, 6);  x0 += k1;  x1 += ks2 + 1u;
  R4(17, 29, 16, 24); x0 += ks2; x1 += k0 + 2u;
  R4(13, 15, 26, 6);  x0 += k0;  x1 += k1 + 3u;
  R4(17, 29, 16, 24); x0 += k1;  x1 += ks2 + 4u;
  R4(13, 15, 26, 6);  x0 += ks2; x1 += k0 + 5u;
  return u2{x0, x1};
#undef R4
#undef ROTL
}

constexpr u2 DK0 = threefry_ce(0u, 7u, 0u, 0u);
constexpr u2 DK1 = threefry_ce(0u, 7u, 0u, 1u);

__device__ __forceinline__ float dropout_scale(int layer, unsigned i) {
  unsigned k0 = layer ? DK1.a : DK0.a;
  unsigned k1 = layer ? DK1.b : DK0.b;
  unsigned ks2 = k0 ^ k1 ^ 0x1BD11BDAu;
  unsigned x0 = 0u + k0, x1 = i + k1;
#define ROTL(v, n) (((v) << (n)) | ((v) >> (32 - (n))))
#define R4(a, b, c, d)                                   \
  { x0 += x1; x1 = ROTL(x1, a); x1 ^= x0;                \
    x0 += x1; x1 = ROTL(x1, b); x1 ^= x0;                \
    x0 += x1; x1 = ROTL(x1, c); x1 ^= x0;                \
    x0 += x1; x1 = ROTL(x1, d); x1 ^= x0; }
  R4(13, 15, 26, 6);  x0 += k1;  x1 += ks2 + 1u;
  R4(17, 29, 16, 24); x0 += ks2; x1 += k0 + 2u;
  R4(13, 15, 26, 6);  x0 += k0;  x1 += k1 + 3u;
  R4(17, 29, 16, 24); x0 += k1;  x1 += ks2 + 4u;
  R4(13, 15, 26, 6);  x0 += ks2; x1 += k0 + 5u;
#undef R4
#undef ROTL
  unsigned bits = x0 ^ x1;
  return (bits & 0x80000000u) ? 0.0f : 2.0f;
}

__device__ __forceinline__ float sigmoidf(float x) {
  return 1.0f / (1.0f + expf(-x));
}

// prod_{t<64}(1-p) < 1e-13 => alignments at t>=64 bounded by ~1e-3 of output
// threshold (telescoping sum x 1e10 clip amplification) -> skippable.
#define CP_CUTOFF 64
#define CP_THRESH 1e-13f

// ---------------------------------------------------------------------------
// 1) Prenet (0..127) + WkT prep (128..191) + h1->bf16 (192..255) +
//    h2->bf16 (256..319).
// ---------------------------------------------------------------------------
__global__ __launch_bounds__(256) void prenet_kernel(
    const float* __restrict__ mels, const float* __restrict__ W1,
    const float* __restrict__ b1, const float* __restrict__ W2,
    const float* __restrict__ b2, const float* __restrict__ Wq,
    const float* __restrict__ Wk, __bf16* __restrict__ WkT,
    const float* __restrict__ h1, __bf16* __restrict__ h1bf,
    const float* __restrict__ h2, __bf16* __restrict__ h2bf,
    float* __restrict__ rnn_in, float* __restrict__ q_out) {
  int blk = blockIdx.x;
  int j = threadIdx.x;
  if (blk >= 256) {  // h2 -> bf16
    int base = (blk - 256) * 2048 + j * 8;
    float4 v0 = *reinterpret_cast<const float4*>(&h2[base]);
    float4 v1 = *reinterpret_cast<const float4*>(&h2[base + 4]);
    bf16x8 w;
    w[0] = (__bf16)v0.x; w[1] = (__bf16)v0.y; w[2] = (__bf16)v0.z; w[3] = (__bf16)v0.w;
    w[4] = (__bf16)v1.x; w[5] = (__bf16)v1.y; w[6] = (__bf16)v1.z; w[7] = (__bf16)v1.w;
    *reinterpret_cast<bf16x8*>(&h2bf[base]) = w;
    return;
  }
  if (blk >= 192) {  // h1 -> bf16
    int base = (blk - 192) * 2048 + j * 8;
    float4 v0 = *reinterpret_cast<const float4*>(&h1[base]);
    float4 v1 = *reinterpret_cast<const float4*>(&h1[base + 4]);
    bf16x8 w;
    w[0] = (__bf16)v0.x; w[1] = (__bf16)v0.y; w[2] = (__bf16)v0.z; w[3] = (__bf16)v0.w;
    w[4] = (__bf16)v1.x; w[5] = (__bf16)v1.y; w[6] = (__bf16)v1.z; w[7] = (__bf16)v1.w;
    *reinterpret_cast<bf16x8*>(&h1bf[base]) = w;
    return;
  }
  if (blk >= 128) {  // WkT prep
    int gid = (blk - 128) * 256 + j;
    int a = gid & 127;
    int k4 = (gid >> 7) * 4;
    bf16x4 w;
    for (int i = 0; i < 4; ++i) w[i] = (__bf16)Wk[(size_t)(k4 + i) * 128 + a];
    *reinterpret_cast<bf16x4*>(&WkT[(size_t)a * 512 + k4]) = w;
    return;
  }
  int b = blk;
  __shared__ float mel_s[80];
  __shared__ float x1_s[256];
  __shared__ float x2_s[256];
  if (j < 80) mel_s[j] = mels[b * 80 + j];
  __syncthreads();
  float s = b1[j];
  for (int m = 0; m < 80; ++m) s = fmaf(mel_s[m], W1[m * 256 + j], s);
  s = fmaxf(s, 0.0f) * dropout_scale(0, (unsigned)(b * 256 + j));
  x1_s[j] = s;
  __syncthreads();
  float s2 = b2[j];
  for (int m = 0; m < 256; ++m) s2 = fmaf(x1_s[m], W2[m * 256 + j], s2);
  s2 = fmaxf(s2, 0.0f) * dropout_scale(1, (unsigned)(b * 256 + j));
  x2_s[j] = s2;
  rnn_in[(size_t)b * 768 + j] = s2;
  __syncthreads();
  if (j < 128) {
    float sq = 0.0f;
    for (int m = 0; m < 256; ++m) sq = fmaf(x2_s[m], Wq[m * 128 + j], sq);
    q_out[b * 128 + j] = sq;
  }
}

// ---------------------------------------------------------------------------
// 2) score for t<64: 16-t tiles, grid (4,128). B-frags from global.
// ---------------------------------------------------------------------------
__global__ __launch_bounds__(256) void score16_kernel(
    const float* __restrict__ enc, const __bf16* __restrict__ WkT,
    const float* __restrict__ bk, const float* __restrict__ q,
    const float* __restrict__ va_g, const float* __restrict__ bscore,
    float* __restrict__ score) {
  int b = blockIdx.y;
  int t0 = blockIdx.x * 16;
  int tid = threadIdx.x;
  int lane = tid & 63, wid = tid >> 6;
  __shared__ __align__(16) __bf16 Eb[16 * 64];
  __shared__ float red[16][4];

  f32x4 acc[2];
#pragma unroll
  for (int j = 0; j < 2; ++j) acc[j] = (f32x4){0.f, 0.f, 0.f, 0.f};

  float qv[2], vav[2];
  int an[2];
#pragma unroll
  for (int j = 0; j < 2; ++j) {
    int a = wid * 32 + j * 16 + (lane & 15);
    an[j] = a;
    qv[j] = q[b * 128 + a] + bk[a];
    vav[j] = va_g[a];
  }
  int er = tid >> 4, ek4 = (tid & 15) * 4;
  int koct = (lane >> 4) * 8;
  int tl = lane & 15;

  for (int k0 = 0; k0 < 512; k0 += 64) {
    __syncthreads();
    {
      const float4 v = *reinterpret_cast<const float4*>(
          &enc[((size_t)(b * 512 + t0 + er)) * 512 + k0 + ek4]);
      bf16x4 w;
      w[0] = (__bf16)v.x; w[1] = (__bf16)v.y;
      w[2] = (__bf16)v.z; w[3] = (__bf16)v.w;
      *reinterpret_cast<bf16x4*>(&Eb[er * 64 + (ek4 ^ ((er & 7) << 3))]) = w;
    }
    __syncthreads();
#pragma unroll
    for (int kk = 0; kk < 64; kk += 32) {
      int kl = kk + koct;
      bf16x8 af = *reinterpret_cast<const bf16x8*>(
          &Eb[tl * 64 + (kl ^ ((tl & 7) << 3))]);
      bf16x8 bfr[2];
#pragma unroll
      for (int j = 0; j < 2; ++j)
        bfr[j] = *reinterpret_cast<const bf16x8*>(
            &WkT[(size_t)an[j] * 512 + k0 + kl]);
#pragma unroll
      for (int j = 0; j < 2; ++j)
        acc[j] = __builtin_amdgcn_mfma_f32_16x16x32_bf16(af, bfr[j], acc[j], 0, 0, 0);
    }
  }

#pragma unroll
  for (int r = 0; r < 4; ++r) {
    float s = tanhf(qv[0] + acc[0][r]) * vav[0] +
              tanhf(qv[1] + acc[1][r]) * vav[1];
    s += __shfl_xor(s, 1, 64);
    s += __shfl_xor(s, 2, 64);
    s += __shfl_xor(s, 4, 64);
    s += __shfl_xor(s, 8, 64);
    if ((lane & 15) == 0) red[(lane >> 4) * 4 + r][wid] = s;
  }
  __syncthreads();
  if (tid < 16)
    score[b * 512 + t0 + tid] =
        red[tid][0] + red[tid][1] + red[tid][2] + red[tid][3] + bscore[0];
}

// ---------------------------------------------------------------------------
// 3) Fused scan + attention context (ballot-bounded). For flagged b, scores
//    at t>=64 are never needed (p=0 exact); for UNFLAGGED b they are computed
//    inline via a scalar dot fallback (same math as the old score64 kernel).
// ---------------------------------------------------------------------------
__global__ __launch_bounds__(512) void scanatt_kernel(
    const float* __restrict__ score, const float* __restrict__ prev_align,
    const float* __restrict__ enc, const __bf16* __restrict__ WkT,
    const float* __restrict__ bk, const float* __restrict__ q,
    const float* __restrict__ va_g, const float* __restrict__ bscore,
    float* __restrict__ align_out, float* __restrict__ rnn_in) {
  int b = blockIdx.x, t = threadIdx.x;
  int lane = t & 63, wv = t >> 6;
  __shared__ float wtot[8];
  __shared__ float flg_s;
  __shared__ float al_s[512];
  __shared__ int wnz[8];
  float sc0 = (t < CP_CUTOFF) ? score[b * 512 + t] : 0.0f;
  if (wv == 0) {  // flag: product of (1-p) over t<64 (wave 0 == t<64)
    float om = 1.0f - sigmoidf(sc0);
    for (int off = 32; off >= 1; off >>= 1) om *= __shfl_xor(om, off, 64);
    if (lane == 0) flg_s = om;
  }
  __syncthreads();
  int flg = flg_s < CP_THRESH;
  float sc = sc0;
  if (t >= CP_CUTOFF) {
    if (flg) {
      sc = -1e30f;  // exact: cp_excl below underflow -> align 0 regardless
    } else {
      // slow exact fallback (never taken when cp underflows for all b):
      // score[t] = bsc + sum_a tanh(q[a]+bk[a] + enc[t,:]@WkT[a,:]) * va[a]
      float sum = 0.0f;
      const float* eb = enc + ((size_t)(b * 512) + t) * 512;
      for (int a = 0; a < 128; ++a) {
        float d = q[b * 128 + a] + bk[a];
        const __bf16* wk = WkT + (size_t)a * 512;
        for (int v = 0; v < 512; ++v) d = fmaf(eb[v], (float)wk[v], d);
        sum = fmaf(tanhf(d), va_g[a], sum);
      }
      sc = sum + bscore[0];
    }
  }
  float p = sigmoidf(sc);
  float x = 1.0f - p;
  // inclusive cumprod: per-wave shuffle scan + wave-offset combine
#pragma unroll
  for (int off = 1; off < 64; off <<= 1) {
    float v = __shfl_up(x, off, 64);
    if (lane >= off) x *= v;
  }
  if (lane == 63) wtot[wv] = x;
  __syncthreads();
  float pre = 1.0f;
  for (int w = 0; w < wv; ++w) pre *= wtot[w];
  x *= pre;
  float xm1 = __shfl_up(x, 1, 64);
  float cp_excl = (lane == 0) ? ((wv == 0) ? 1.0f : pre) : xm1;
  float denom = fminf(fmaxf(cp_excl, 1e-10f), 1.0f);
  float r = prev_align[b * 512 + t] / denom;
  float y = r;
#pragma unroll
  for (int off = 1; off < 64; off <<= 1) {
    float v = __shfl_up(y, off, 64);
    if (lane >= off) y += v;
  }
  __syncthreads();
  if (lane == 63) wtot[wv] = y;
  __syncthreads();
  float spre = 0.0f;
  for (int w = 0; w < wv; ++w) spre += wtot[w];
  y += spre;
  float align = p * cp_excl * y;
  align_out[b * 512 + t] = align;
  al_s[t] = align;
  unsigned long long m = __ballot(align != 0.0f);
  if (lane == 0) wnz[wv] = m ? (wv * 64 + 63 - __clzll(m)) : -1;
  __syncthreads();
  int ln = -1;
#pragma unroll
  for (int w = 0; w < 8; ++w) ln = max(ln, wnz[w]);
  float acc = 0.0f;
  const float* encb = enc + (size_t)b * 512 * 512 + t;
  for (int tt = 0; tt <= ln; ++tt)
    acc = fmaf(al_s[tt], encb[(size_t)tt * 512], acc);
  rnn_in[(size_t)b * 768 + 256 + t] = acc;
}

// ---------------------------------------------------------------------------
// 5) LSTM z partials via MFMA: grid (128,4) = 512 blocks; LDS-staged A.
// ---------------------------------------------------------------------------
__global__ __launch_bounds__(256) void zgemm_mfma_kernel(
    const float* __restrict__ A0, const __bf16* __restrict__ Abf0, int K0,
    const float* __restrict__ W0,
    const float* __restrict__ A1, const __bf16* __restrict__ Abf1, int K1,
    const float* __restrict__ W1,
    float* __restrict__ parts) {
  int cb = blockIdx.x;   // 0..127 (32-wide col blocks)
  int zp = blockIdx.y;   // 0..3
  int seg = zp >> 1, kh = zp & 1;
  const float* A = seg ? A1 : A0;
  const __bf16* Abf = seg ? Abf1 : Abf0;
  const float* W = seg ? W1 : W0;
  int K = seg ? K1 : K0;
  int kc = K >> 1;
  int kbeg = kh * kc, kend = kbeg + kc;
  int tid = threadIdx.x;
  int lane = tid & 63, wid = tid >> 6;
  int wr = wid >> 1, wc = wid & 1;
  __shared__ __align__(16) __bf16 Ab[128 * 64];

  f32x4 acc[4];
#pragma unroll
  for (int i = 0; i < 4; ++i) acc[i] = (f32x4){0.f, 0.f, 0.f, 0.f};

  int n_base = cb * 32 + wc * 16 + (lane & 15);
  int koct = (lane >> 4) * 8;

  for (int k0 = kbeg; k0 < kend; k0 += 64) {
    __syncthreads();
    if (Abf) {  // bf16 source: 16B loads, swizzle-preserving 16B stores
      int r4 = tid >> 3;         // 0..31
      int k8 = (tid & 7) * 8;    // 0..56
#pragma unroll
      for (int p = 0; p < 4; ++p) {
        int row = r4 + p * 32;
        bf16x8 v = *reinterpret_cast<const bf16x8*>(
            &Abf[(size_t)row * K + k0 + k8]);
        *reinterpret_cast<bf16x8*>(&Ab[row * 64 + (k8 ^ ((row & 7) << 3))]) = v;
      }
    } else {
      int r = tid >> 4;
      int k4 = (tid & 15) * 4;
#pragma unroll
      for (int p = 0; p < 8; ++p) {
        int row = r + p * 16;
        const float4 v = *reinterpret_cast<const float4*>(
            &A[(size_t)row * K + k0 + k4]);
        bf16x4 w;
        w[0] = (__bf16)v.x; w[1] = (__bf16)v.y;
        w[2] = (__bf16)v.z; w[3] = (__bf16)v.w;
        *reinterpret_cast<bf16x4*>(&Ab[row * 64 + (k4 ^ ((row & 7) << 3))]) = w;
      }
    }
    __syncthreads();
#pragma unroll
    for (int kk = 0; kk < 64; kk += 32) {
      const float* wq = W + (size_t)(k0 + kk + koct) * 4096 + n_base;
      bf16x8 bfr;
#pragma unroll
      for (int j = 0; j < 8; ++j) bfr[j] = (__bf16)wq[(size_t)j * 4096];
      int kl = kk + koct;
#pragma unroll
      for (int i = 0; i < 4; ++i) {
        int t = wr * 64 + i * 16 + (lane & 15);
        bf16x8 af = *reinterpret_cast<const bf16x8*>(
            &Ab[t * 64 + (kl ^ ((t & 7) << 3))]);
        acc[i] = __builtin_amdgcn_mfma_f32_16x16x32_bf16(af, bfr, acc[i], 0, 0, 0);
      }
    }
  }

  float* outp = parts + (size_t)zp * (128 * 4096);
#pragma unroll
  for (int i = 0; i < 4; ++i)
#pragma unroll
    for (int r = 0; r < 4; ++r) {
      int row = wr * 64 + i * 16 + ((lane >> 4) << 2) + r;
      int col = cb * 32 + wc * 16 + (lane & 15);
      outp[(size_t)row * 4096 + col] = acc[i][r];
    }
}

// ---------------------------------------------------------------------------
// 6) LSTM gate (layer 1): z = sum of 4 parts + bias; also writes h1n as bf16.
// ---------------------------------------------------------------------------
__global__ __launch_bounds__(256) void gate_kernel(
    const float* __restrict__ parts, const float* __restrict__ bias,
    const float* __restrict__ c_prev, float* __restrict__ h_out,
    float* __restrict__ c_out, __bf16* __restrict__ h_bf) {
  int idx = blockIdx.x * 256 + threadIdx.x;
  int b = idx >> 10, j = idx & 1023;
  float zv[4];
  for (int g = 0; g < 4; ++g) {
    size_t off = (size_t)b * 4096 + g * 1024 + j;
    float s = bias[g * 1024 + j];
    for (int p = 0; p < 4; ++p) s += parts[(size_t)p * (128 * 4096) + off];
    zv[g] = s;
  }
  float ig = sigmoidf(zv[0]);
  float fg = sigmoidf(zv[1]);
  float gg = tanhf(zv[2]);
  float og = sigmoidf(zv[3]);
  float cn = fg * c_prev[idx] + ig * gg;
  float hn = og * tanhf(cn);
  h_out[idx] = hn;
  c_out[idx] = cn;
  h_bf[idx] = (__bf16)hn;
}

// ---------------------------------------------------------------------------
// 6b) Fused gate2 + projection: one block per b (1024 threads).
// ---------------------------------------------------------------------------
__global__ __launch_bounds__(1024) void gateproj_kernel(
    const float* __restrict__ parts, const float* __restrict__ bias,
    const float* __restrict__ c_prev, const float* __restrict__ rnn_in,
    const float* __restrict__ Wp, const float* __restrict__ bp,
    float* __restrict__ h_out, float* __restrict__ c_out,
    float* __restrict__ mel, float* __restrict__ stops) {
  int b = blockIdx.x;
  int j = threadIdx.x;
  __shared__ float row[1536];
  __shared__ float red[12][81];
  int idx = b * 1024 + j;
  float zv[4];
#pragma unroll
  for (int g = 0; g < 4; ++g) {
    size_t off = (size_t)b * 4096 + g * 1024 + j;
    float s = bias[g * 1024 + j];
#pragma unroll
    for (int p = 0; p < 4; ++p) s += parts[(size_t)p * (128 * 4096) + off];
    zv[g] = s;
  }
  float ig = sigmoidf(zv[0]);
  float fg = sigmoidf(zv[1]);
  float gg = tanhf(zv[2]);
  float og = sigmoidf(zv[3]);
  float cn = fg * c_prev[idx] + ig * gg;
  float hn = og * tanhf(cn);
  h_out[idx] = hn;
  c_out[idx] = cn;
  row[j] = hn;
  if (j < 512) row[1024 + j] = rnn_in[(size_t)b * 768 + 256 + j];
  __syncthreads();
  if (j < 972) {
    int o = j % 81, part = j / 81;
    int m0 = part * 128;
    float s = 0.0f;
    for (int m = m0; m < m0 + 128; ++m) s = fmaf(row[m], Wp[m * 81 + o], s);
    red[part][o] = s;
  }
  __syncthreads();
  if (j < 81) {
    float s = bp[j];
#pragma unroll
    for (int p = 0; p < 12; ++p) s += red[p][j];
    if (j < 80) mel[b * 80 + j] = s;
    else stops[b] = s;
  }
}

// ---------------------------------------------------------------------------
extern "C" void kernel_launch(void* const* d_in, const int* in_sizes, int n_in,
                              void* d_out, int out_size, void* d_ws,
                              size_t ws_size, hipStream_t stream) {
  const float* enc  = (const float*)d_in[0];
  const float* mels = (const float*)d_in[1];
  const float* prev = (const float*)d_in[2];
  const float* h1   = (const float*)d_in[3];
  const float* c1   = (const float*)d_in[4];
  const float* h2   = (const float*)d_in[5];
  const float* c2   = (const float*)d_in[6];
  const float* Wp1  = (const float*)d_in[7];
  const float* bp1  = (const float*)d_in[8];
  const float* Wp2  = (const float*)d_in[9];
  const float* bp2  = (const float*)d_in[10];
  const float* Wq   = (const float*)d_in[11];
  const float* Wk   = (const float*)d_in[12];
  const float* bk   = (const float*)d_in[13];
  const float* va   = (const float*)d_in[14];
  const float* bsc  = (const float*)d_in[15];
  const float* Wx1  = (const float*)d_in[16];
  const float* Wh1  = (const float*)d_in[17];
  const float* bl1  = (const float*)d_in[18];
  const float* Wx2  = (const float*)d_in[19];
  const float* Wh2  = (const float*)d_in[20];
  const float* bl2  = (const float*)d_in[21];
  const float* Wpj  = (const float*)d_in[22];
  const float* bpj  = (const float*)d_in[23];

  float* out = (float*)d_out;
  float* mel    = out;            // 128*80
  float* stops  = out + 10240;    // 128
  float* aligno = out + 10368;    // 128*512
  float* h1n    = out + 75904;    // 128*1024
  float* c1n    = out + 206976;
  float* h2n    = out + 338048;
  float* c2n    = out + 469120;

  float* ws = (float*)d_ws;
  float* q_ws   = ws;              // 16384
  float* sc_ws  = ws + 16384;      // 65536
  float* rnn_in = ws + 81920;      // 98304
  float* parts  = ws + 180224;     // 4 * 524288 = 2,097,152
  __bf16* h1bf  = (__bf16*)(ws + 2277376);  // 131072 bf16 = 65536 f
  __bf16* h2bf  = (__bf16*)(ws + 2342912);
  __bf16* h1nbf = (__bf16*)(ws + 2408448);
  // WkT bf16: lives past scanatt now, so give it its own slot (not parts).
  __bf16* WkT   = (__bf16*)(ws + 2473984);  // 65536 bf16 = 32768 f

  hipLaunchKernelGGL(prenet_kernel, dim3(320), dim3(256), 0, stream,
                     mels, Wp1, bp1, Wp2, bp2, Wq, Wk, WkT,
                     h1, h1bf, h2, h2bf, rnn_in, q_ws);
  hipLaunchKernelGGL(score16_kernel, dim3(4, 128), dim3(256), 0, stream,
                     enc, WkT, bk, q_ws, va, bsc, sc_ws);
  hipLaunchKernelGGL(scanatt_kernel, dim3(128), dim3(512), 0, stream,
                     sc_ws, prev, enc, WkT, bk, q_ws, va, bsc, aligno, rnn_in);
  hipLaunchKernelGGL(zgemm_mfma_kernel, dim3(128, 4), dim3(256), 0, stream,
                     rnn_in, (const __bf16*)nullptr, 768, Wx1,
                     h1, h1bf, 1024, Wh1, parts);
  hipLaunchKernelGGL(gate_kernel, dim3(512), dim3(256), 0, stream,
                     parts, bl1, c1, h1n, c1n, h1nbf);
  hipLaunchKernelGGL(zgemm_mfma_kernel, dim3(128, 4), dim3(256), 0, stream,
                     h1n, h1nbf, 1024, Wx2,
                     h2, h2bf, 1024, Wh2, parts);
  hipLaunchKernelGGL(gateproj_kernel, dim3(128), dim3(1024), 0, stream,
                     parts, bl2, c2, rnn_in, Wpj, bpj, h2n, c2n, mel, stops);
}

// Round 21
// 76.354 us; speedup vs baseline: 1.2064x; 1.0183x over previous
//
#include <hip/hip_runtime.h>
#include <math.h>

typedef float f32x4 __attribute__((ext_vector_type(4)));
typedef __bf16 bf16x8 __attribute__((ext_vector_type(8)));
typedef __bf16 bf16x4 __attribute__((ext_vector_type(4)));

// ---------------------------------------------------------------------------
// JAX threefry2x32 (exact port) + dropout mask replication.
// ---------------------------------------------------------------------------
struct u2 { unsigned a, b; };

__host__ __device__ constexpr u2 threefry_ce(unsigned k0, unsigned k1,
                                             unsigned c0, unsigned c1) {
  unsigned ks2 = k0 ^ k1 ^ 0x1BD11BDAu;
  unsigned x0 = c0 + k0, x1 = c1 + k1;
#define ROTL(v, n) (((v) << (n)) | ((v) >> (32 - (n))))
#define R4(a, b, c, d)                                   \
  { x0 += x1; x1 = ROTL(x1, a); x1 ^= x0;                \
    x0 += x1; x1 = ROTL(x1, b); x1 ^= x0;                \
    x0 += x1; x1 = ROTL(x1, c); x1 ^= x0;                \
    x0 += x1; x1 = ROTL(x1, d); x1 ^= x0; }
  R4(13, 15, 26, 6);  x0 += k1;  x1 += ks2 + 1u;
  R4(17, 29, 16, 24); x0 += ks2; x1 += k0 + 2u;
  R4(13, 15, 26, 6);  x0 += k0;  x1 += k1 + 3u;
  R4(17, 29, 16, 24); x0 += k1;  x1 += ks2 + 4u;
  R4(13, 15, 26, 6);  x0 += ks2; x1 += k0 + 5u;
  return u2{x0, x1};
#undef R4
#undef ROTL
}

constexpr u2 DK0 = threefry_ce(0u, 7u, 0u, 0u);
constexpr u2 DK1 = threefry_ce(0u, 7u, 0u, 1u);

__device__ __forceinline__ float dropout_scale(int layer, unsigned i) {
  unsigned k0 = layer ? DK1.a : DK0.a;
  unsigned k1 = layer ? DK1.b : DK0.b;
  unsigned ks2 = k0 ^ k1 ^ 0x1BD11BDAu;
  unsigned x0 = 0u + k0, x1 = i + k1;
#define ROTL(v, n) (((v) << (n)) | ((v) >> (32 - (n))))
#define R4(a, b, c, d)                                   \
  { x0 += x1; x1 = ROTL(x1, a); x1 ^= x0;                \
    x0 += x1; x1 = ROTL(x1, b); x1 ^= x0;                \
    x0 += x1; x1 = ROTL(x1, c); x1 ^= x0;                \
    x0 += x1; x1 = ROTL(x1, d); x1 ^= x0; }
  R4(13, 15, 26, 6);  x0 += k1;  x1 += ks2 + 1u;
  R4(17, 29, 16, 24); x0 += ks2; x1 += k0 + 2u;
  R4(13, 15, 26, 6);  x0 += k0;  x1 += k1 + 3u;
  R4(17, 29, 16, 24); x0 += k1;  x1 += ks2 + 4u;
  R4(13, 15, 26, 6);  x0 += ks2; x1 += k0 + 5u;
#undef R4
#undef ROTL
  unsigned bits = x0 ^ x1;
  return (bits & 0x80000000u) ? 0.0f : 2.0f;
}

__device__ __forceinline__ float sigmoidf(float x) {
  return 1.0f / (1.0f + expf(-x));
}

// prod_{t<64}(1-p) < 1e-13 => alignments at t>=64 bounded by ~1e-3 of output
// threshold (telescoping sum x 1e10 clip amplification) -> skippable.
#define CP_CUTOFF 64
#define CP_THRESH 1e-13f

// ---------------------------------------------------------------------------
// 1) Prenet (0..127) + WkT prep (128..191) + h1->bf16 (192..255) +
//    h2->bf16 (256..319).
// ---------------------------------------------------------------------------
__global__ __launch_bounds__(256) void prenet_kernel(
    const float* __restrict__ mels, const float* __restrict__ W1,
    const float* __restrict__ b1, const float* __restrict__ W2,
    const float* __restrict__ b2, const float* __restrict__ Wq,
    const float* __restrict__ Wk, __bf16* __restrict__ WkT,
    const float* __restrict__ h1, __bf16* __restrict__ h1bf,
    const float* __restrict__ h2, __bf16* __restrict__ h2bf,
    float* __restrict__ rnn_in, float* __restrict__ q_out) {
  int blk = blockIdx.x;
  int j = threadIdx.x;
  if (blk >= 256) {  // h2 -> bf16
    int base = (blk - 256) * 2048 + j * 8;
    float4 v0 = *reinterpret_cast<const float4*>(&h2[base]);
    float4 v1 = *reinterpret_cast<const float4*>(&h2[base + 4]);
    bf16x8 w;
    w[0] = (__bf16)v0.x; w[1] = (__bf16)v0.y; w[2] = (__bf16)v0.z; w[3] = (__bf16)v0.w;
    w[4] = (__bf16)v1.x; w[5] = (__bf16)v1.y; w[6] = (__bf16)v1.z; w[7] = (__bf16)v1.w;
    *reinterpret_cast<bf16x8*>(&h2bf[base]) = w;
    return;
  }
  if (blk >= 192) {  // h1 -> bf16
    int base = (blk - 192) * 2048 + j * 8;
    float4 v0 = *reinterpret_cast<const float4*>(&h1[base]);
    float4 v1 = *reinterpret_cast<const float4*>(&h1[base + 4]);
    bf16x8 w;
    w[0] = (__bf16)v0.x; w[1] = (__bf16)v0.y; w[2] = (__bf16)v0.z; w[3] = (__bf16)v0.w;
    w[4] = (__bf16)v1.x; w[5] = (__bf16)v1.y; w[6] = (__bf16)v1.z; w[7] = (__bf16)v1.w;
    *reinterpret_cast<bf16x8*>(&h1bf[base]) = w;
    return;
  }
  if (blk >= 128) {  // WkT prep
    int gid = (blk - 128) * 256 + j;
    int a = gid & 127;
    int k4 = (gid >> 7) * 4;
    bf16x4 w;
    for (int i = 0; i < 4; ++i) w[i] = (__bf16)Wk[(size_t)(k4 + i) * 128 + a];
    *reinterpret_cast<bf16x4*>(&WkT[(size_t)a * 512 + k4]) = w;
    return;
  }
  int b = blk;
  __shared__ float mel_s[80];
  __shared__ float x1_s[256];
  __shared__ float x2_s[256];
  if (j < 80) mel_s[j] = mels[b * 80 + j];
  __syncthreads();
  float s = b1[j];
  for (int m = 0; m < 80; ++m) s = fmaf(mel_s[m], W1[m * 256 + j], s);
  s = fmaxf(s, 0.0f) * dropout_scale(0, (unsigned)(b * 256 + j));
  x1_s[j] = s;
  __syncthreads();
  float s2 = b2[j];
  for (int m = 0; m < 256; ++m) s2 = fmaf(x1_s[m], W2[m * 256 + j], s2);
  s2 = fmaxf(s2, 0.0f) * dropout_scale(1, (unsigned)(b * 256 + j));
  x2_s[j] = s2;
  rnn_in[(size_t)b * 768 + j] = s2;
  __syncthreads();
  if (j < 128) {
    float sq = 0.0f;
    for (int m = 0; m < 256; ++m) sq = fmaf(x2_s[m], Wq[m * 128 + j], sq);
    q_out[b * 128 + j] = sq;
  }
}

// ---------------------------------------------------------------------------
// 2) score for t<64: 16-t tiles, grid (4,128). B-frags from global.
// ---------------------------------------------------------------------------
__global__ __launch_bounds__(256) void score16_kernel(
    const float* __restrict__ enc, const __bf16* __restrict__ WkT,
    const float* __restrict__ bk, const float* __restrict__ q,
    const float* __restrict__ va_g, const float* __restrict__ bscore,
    float* __restrict__ score) {
  int b = blockIdx.y;
  int t0 = blockIdx.x * 16;
  int tid = threadIdx.x;
  int lane = tid & 63, wid = tid >> 6;
  __shared__ __align__(16) __bf16 Eb[16 * 64];
  __shared__ float red[16][4];

  f32x4 acc[2];
#pragma unroll
  for (int j = 0; j < 2; ++j) acc[j] = (f32x4){0.f, 0.f, 0.f, 0.f};

  float qv[2], vav[2];
  int an[2];
#pragma unroll
  for (int j = 0; j < 2; ++j) {
    int a = wid * 32 + j * 16 + (lane & 15);
    an[j] = a;
    qv[j] = q[b * 128 + a] + bk[a];
    vav[j] = va_g[a];
  }
  int er = tid >> 4, ek4 = (tid & 15) * 4;
  int koct = (lane >> 4) * 8;
  int tl = lane & 15;

  for (int k0 = 0; k0 < 512; k0 += 64) {
    __syncthreads();
    {
      const float4 v = *reinterpret_cast<const float4*>(
          &enc[((size_t)(b * 512 + t0 + er)) * 512 + k0 + ek4]);
      bf16x4 w;
      w[0] = (__bf16)v.x; w[1] = (__bf16)v.y;
      w[2] = (__bf16)v.z; w[3] = (__bf16)v.w;
      *reinterpret_cast<bf16x4*>(&Eb[er * 64 + (ek4 ^ ((er & 7) << 3))]) = w;
    }
    __syncthreads();
#pragma unroll
    for (int kk = 0; kk < 64; kk += 32) {
      int kl = kk + koct;
      bf16x8 af = *reinterpret_cast<const bf16x8*>(
          &Eb[tl * 64 + (kl ^ ((tl & 7) << 3))]);
      bf16x8 bfr[2];
#pragma unroll
      for (int j = 0; j < 2; ++j)
        bfr[j] = *reinterpret_cast<const bf16x8*>(
            &WkT[(size_t)an[j] * 512 + k0 + kl]);
#pragma unroll
      for (int j = 0; j < 2; ++j)
        acc[j] = __builtin_amdgcn_mfma_f32_16x16x32_bf16(af, bfr[j], acc[j], 0, 0, 0);
    }
  }

#pragma unroll
  for (int r = 0; r < 4; ++r) {
    float s = tanhf(qv[0] + acc[0][r]) * vav[0] +
              tanhf(qv[1] + acc[1][r]) * vav[1];
    s += __shfl_xor(s, 1, 64);
    s += __shfl_xor(s, 2, 64);
    s += __shfl_xor(s, 4, 64);
    s += __shfl_xor(s, 8, 64);
    if ((lane & 15) == 0) red[(lane >> 4) * 4 + r][wid] = s;
  }
  __syncthreads();
  if (tid < 16)
    score[b * 512 + t0 + tid] =
        red[tid][0] + red[tid][1] + red[tid][2] + red[tid][3] + bscore[0];
}

// ---------------------------------------------------------------------------
// 3) Fused scan + attention context (ballot-bounded). For flagged b, scores
//    at t>=64 are never needed (p=0 exact); for UNFLAGGED b they are computed
//    inline via a scalar dot fallback (same math as the old score64 kernel).
// ---------------------------------------------------------------------------
__global__ __launch_bounds__(512) void scanatt_kernel(
    const float* __restrict__ score, const float* __restrict__ prev_align,
    const float* __restrict__ enc, const __bf16* __restrict__ WkT,
    const float* __restrict__ bk, const float* __restrict__ q,
    const float* __restrict__ va_g, const float* __restrict__ bscore,
    float* __restrict__ align_out, float* __restrict__ rnn_in) {
  int b = blockIdx.x, t = threadIdx.x;
  int lane = t & 63, wv = t >> 6;
  __shared__ float wtot[8];
  __shared__ float flg_s;
  __shared__ float al_s[512];
  __shared__ int wnz[8];
  float sc0 = (t < CP_CUTOFF) ? score[b * 512 + t] : 0.0f;
  if (wv == 0) {  // flag: product of (1-p) over t<64 (wave 0 == t<64)
    float om = 1.0f - sigmoidf(sc0);
    for (int off = 32; off >= 1; off >>= 1) om *= __shfl_xor(om, off, 64);
    if (lane == 0) flg_s = om;
  }
  __syncthreads();
  int flg = flg_s < CP_THRESH;
  float sc = sc0;
  if (t >= CP_CUTOFF) {
    if (flg) {
      sc = -1e30f;  // exact: cp_excl below underflow -> align 0 regardless
    } else {
      // slow exact fallback (never taken when cp underflows for all b):
      float sum = 0.0f;
      const float* eb = enc + ((size_t)(b * 512) + t) * 512;
      for (int a = 0; a < 128; ++a) {
        float d = q[b * 128 + a] + bk[a];
        const __bf16* wk = WkT + (size_t)a * 512;
        for (int v = 0; v < 512; ++v) d = fmaf(eb[v], (float)wk[v], d);
        sum = fmaf(tanhf(d), va_g[a], sum);
      }
      sc = sum + bscore[0];
    }
  }
  float p = sigmoidf(sc);
  float x = 1.0f - p;
#pragma unroll
  for (int off = 1; off < 64; off <<= 1) {
    float v = __shfl_up(x, off, 64);
    if (lane >= off) x *= v;
  }
  if (lane == 63) wtot[wv] = x;
  __syncthreads();
  float pre = 1.0f;
  for (int w = 0; w < wv; ++w) pre *= wtot[w];
  x *= pre;
  float xm1 = __shfl_up(x, 1, 64);
  float cp_excl = (lane == 0) ? ((wv == 0) ? 1.0f : pre) : xm1;
  float denom = fminf(fmaxf(cp_excl, 1e-10f), 1.0f);
  float r = prev_align[b * 512 + t] / denom;
  float y = r;
#pragma unroll
  for (int off = 1; off < 64; off <<= 1) {
    float v = __shfl_up(y, off, 64);
    if (lane >= off) y += v;
  }
  __syncthreads();
  if (lane == 63) wtot[wv] = y;
  __syncthreads();
  float spre = 0.0f;
  for (int w = 0; w < wv; ++w) spre += wtot[w];
  y += spre;
  float align = p * cp_excl * y;
  align_out[b * 512 + t] = align;
  al_s[t] = align;
  unsigned long long m = __ballot(align != 0.0f);
  if (lane == 0) wnz[wv] = m ? (wv * 64 + 63 - __clzll(m)) : -1;
  __syncthreads();
  int ln = -1;
#pragma unroll
  for (int w = 0; w < 8; ++w) ln = max(ln, wnz[w]);
  float acc = 0.0f;
  const float* encb = enc + (size_t)b * 512 * 512 + t;
  for (int tt = 0; tt <= ln; ++tt)
    acc = fmaf(al_s[tt], encb[(size_t)tt * 512], acc);
  rnn_in[(size_t)b * 768 + 256 + t] = acc;
}

// ---------------------------------------------------------------------------
// 5) LSTM z partials via MFMA: grid (128,4) = 512 blocks; LDS-staged A.
//    Partials stored as BF16 (halves the parts round-trip).
// ---------------------------------------------------------------------------
__global__ __launch_bounds__(256) void zgemm_mfma_kernel(
    const float* __restrict__ A0, const __bf16* __restrict__ Abf0, int K0,
    const float* __restrict__ W0,
    const float* __restrict__ A1, const __bf16* __restrict__ Abf1, int K1,
    const float* __restrict__ W1,
    __bf16* __restrict__ parts) {
  int cb = blockIdx.x;   // 0..127 (32-wide col blocks)
  int zp = blockIdx.y;   // 0..3
  int seg = zp >> 1, kh = zp & 1;
  const float* A = seg ? A1 : A0;
  const __bf16* Abf = seg ? Abf1 : Abf0;
  const float* W = seg ? W1 : W0;
  int K = seg ? K1 : K0;
  int kc = K >> 1;
  int kbeg = kh * kc, kend = kbeg + kc;
  int tid = threadIdx.x;
  int lane = tid & 63, wid = tid >> 6;
  int wr = wid >> 1, wc = wid & 1;
  __shared__ __align__(16) __bf16 Ab[128 * 64];

  f32x4 acc[4];
#pragma unroll
  for (int i = 0; i < 4; ++i) acc[i] = (f32x4){0.f, 0.f, 0.f, 0.f};

  int n_base = cb * 32 + wc * 16 + (lane & 15);
  int koct = (lane >> 4) * 8;

  for (int k0 = kbeg; k0 < kend; k0 += 64) {
    __syncthreads();
    if (Abf) {  // bf16 source: 16B loads, swizzle-preserving 16B stores
      int r4 = tid >> 3;         // 0..31
      int k8 = (tid & 7) * 8;    // 0..56
#pragma unroll
      for (int p = 0; p < 4; ++p) {
        int row = r4 + p * 32;
        bf16x8 v = *reinterpret_cast<const bf16x8*>(
            &Abf[(size_t)row * K + k0 + k8]);
        *reinterpret_cast<bf16x8*>(&Ab[row * 64 + (k8 ^ ((row & 7) << 3))]) = v;
      }
    } else {
      int r = tid >> 4;
      int k4 = (tid & 15) * 4;
#pragma unroll
      for (int p = 0; p < 8; ++p) {
        int row = r + p * 16;
        const float4 v = *reinterpret_cast<const float4*>(
            &A[(size_t)row * K + k0 + k4]);
        bf16x4 w;
        w[0] = (__bf16)v.x; w[1] = (__bf16)v.y;
        w[2] = (__bf16)v.z; w[3] = (__bf16)v.w;
        *reinterpret_cast<bf16x4*>(&Ab[row * 64 + (k4 ^ ((row & 7) << 3))]) = w;
      }
    }
    __syncthreads();
#pragma unroll
    for (int kk = 0; kk < 64; kk += 32) {
      const float* wq = W + (size_t)(k0 + kk + koct) * 4096 + n_base;
      bf16x8 bfr;
#pragma unroll
      for (int j = 0; j < 8; ++j) bfr[j] = (__bf16)wq[(size_t)j * 4096];
      int kl = kk + koct;
#pragma unroll
      for (int i = 0; i < 4; ++i) {
        int t = wr * 64 + i * 16 + (lane & 15);
        bf16x8 af = *reinterpret_cast<const bf16x8*>(
            &Ab[t * 64 + (kl ^ ((t & 7) << 3))]);
        acc[i] = __builtin_amdgcn_mfma_f32_16x16x32_bf16(af, bfr, acc[i], 0, 0, 0);
      }
    }
  }

  __bf16* outp = parts + (size_t)zp * (128 * 4096);
#pragma unroll
  for (int i = 0; i < 4; ++i)
#pragma unroll
    for (int r = 0; r < 4; ++r) {
      int row = wr * 64 + i * 16 + ((lane >> 4) << 2) + r;
      int col = cb * 32 + wc * 16 + (lane & 15);
      outp[(size_t)row * 4096 + col] = (__bf16)acc[i][r];
    }
}

// ---------------------------------------------------------------------------
// 6) LSTM gate (layer 1): z = sum of 4 bf16 parts + bias; h1n also bf16.
// ---------------------------------------------------------------------------
__global__ __launch_bounds__(256) void gate_kernel(
    const __bf16* __restrict__ parts, const float* __restrict__ bias,
    const float* __restrict__ c_prev, float* __restrict__ h_out,
    float* __restrict__ c_out, __bf16* __restrict__ h_bf) {
  int idx = blockIdx.x * 256 + threadIdx.x;
  int b = idx >> 10, j = idx & 1023;
  float zv[4];
  for (int g = 0; g < 4; ++g) {
    size_t off = (size_t)b * 4096 + g * 1024 + j;
    float s = bias[g * 1024 + j];
    for (int p = 0; p < 4; ++p) s += (float)parts[(size_t)p * (128 * 4096) + off];
    zv[g] = s;
  }
  float ig = sigmoidf(zv[0]);
  float fg = sigmoidf(zv[1]);
  float gg = tanhf(zv[2]);
  float og = sigmoidf(zv[3]);
  float cn = fg * c_prev[idx] + ig * gg;
  float hn = og * tanhf(cn);
  h_out[idx] = hn;
  c_out[idx] = cn;
  h_bf[idx] = (__bf16)hn;
}

// ---------------------------------------------------------------------------
// 6b) Fused gate2 + projection: one block per b (1024 threads).
// ---------------------------------------------------------------------------
__global__ __launch_bounds__(1024) void gateproj_kernel(
    const __bf16* __restrict__ parts, const float* __restrict__ bias,
    const float* __restrict__ c_prev, const float* __restrict__ rnn_in,
    const float* __restrict__ Wp, const float* __restrict__ bp,
    float* __restrict__ h_out, float* __restrict__ c_out,
    float* __restrict__ mel, float* __restrict__ stops) {
  int b = blockIdx.x;
  int j = threadIdx.x;
  __shared__ float row[1536];
  __shared__ float red[12][81];
  int idx = b * 1024 + j;
  float zv[4];
#pragma unroll
  for (int g = 0; g < 4; ++g) {
    size_t off = (size_t)b * 4096 + g * 1024 + j;
    float s = bias[g * 1024 + j];
#pragma unroll
    for (int p = 0; p < 4; ++p) s += (float)parts[(size_t)p * (128 * 4096) + off];
    zv[g] = s;
  }
  float ig = sigmoidf(zv[0]);
  float fg = sigmoidf(zv[1]);
  float gg = tanhf(zv[2]);
  float og = sigmoidf(zv[3]);
  float cn = fg * c_prev[idx] + ig * gg;
  float hn = og * tanhf(cn);
  h_out[idx] = hn;
  c_out[idx] = cn;
  row[j] = hn;
  if (j < 512) row[1024 + j] = rnn_in[(size_t)b * 768 + 256 + j];
  __syncthreads();
  if (j < 972) {
    int o = j % 81, part = j / 81;
    int m0 = part * 128;
    float s = 0.0f;
    for (int m = m0; m < m0 + 128; ++m) s = fmaf(row[m], Wp[m * 81 + o], s);
    red[part][o] = s;
  }
  __syncthreads();
  if (j < 81) {
    float s = bp[j];
#pragma unroll
    for (int p = 0; p < 12; ++p) s += red[p][j];
    if (j < 80) mel[b * 80 + j] = s;
    else stops[b] = s;
  }
}

// ---------------------------------------------------------------------------
extern "C" void kernel_launch(void* const* d_in, const int* in_sizes, int n_in,
                              void* d_out, int out_size, void* d_ws,
                              size_t ws_size, hipStream_t stream) {
  const float* enc  = (const float*)d_in[0];
  const float* mels = (const float*)d_in[1];
  const float* prev = (const float*)d_in[2];
  const float* h1   = (const float*)d_in[3];
  const float* c1   = (const float*)d_in[4];
  const float* h2   = (const float*)d_in[5];
  const float* c2   = (const float*)d_in[6];
  const float* Wp1  = (const float*)d_in[7];
  const float* bp1  = (const float*)d_in[8];
  const float* Wp2  = (const float*)d_in[9];
  const float* bp2  = (const float*)d_in[10];
  const float* Wq   = (const float*)d_in[11];
  const float* Wk   = (const float*)d_in[12];
  const float* bk   = (const float*)d_in[13];
  const float* va   = (const float*)d_in[14];
  const float* bsc  = (const float*)d_in[15];
  const float* Wx1  = (const float*)d_in[16];
  const float* Wh1  = (const float*)d_in[17];
  const float* bl1  = (const float*)d_in[18];
  const float* Wx2  = (const float*)d_in[19];
  const float* Wh2  = (const float*)d_in[20];
  const float* bl2  = (const float*)d_in[21];
  const float* Wpj  = (const float*)d_in[22];
  const float* bpj  = (const float*)d_in[23];

  float* out = (float*)d_out;
  float* mel    = out;            // 128*80
  float* stops  = out + 10240;    // 128
  float* aligno = out + 10368;    // 128*512
  float* h1n    = out + 75904;    // 128*1024
  float* c1n    = out + 206976;
  float* h2n    = out + 338048;
  float* c2n    = out + 469120;

  float* ws = (float*)d_ws;
  float* q_ws   = ws;              // 16384
  float* sc_ws  = ws + 16384;      // 65536
  float* rnn_in = ws + 81920;      // 98304
  __bf16* parts = (__bf16*)(ws + 180224);   // 4 * 524288 bf16 = 4 MB
  __bf16* h1bf  = (__bf16*)(ws + 2277376);  // 131072 bf16
  __bf16* h2bf  = (__bf16*)(ws + 2342912);
  __bf16* h1nbf = (__bf16*)(ws + 2408448);
  __bf16* WkT   = (__bf16*)(ws + 2473984);  // 65536 bf16

  hipLaunchKernelGGL(prenet_kernel, dim3(320), dim3(256), 0, stream,
                     mels, Wp1, bp1, Wp2, bp2, Wq, Wk, WkT,
                     h1, h1bf, h2, h2bf, rnn_in, q_ws);
  hipLaunchKernelGGL(score16_kernel, dim3(4, 128), dim3(256), 0, stream,
                     enc, WkT, bk, q_ws, va, bsc, sc_ws);
  hipLaunchKernelGGL(scanatt_kernel, dim3(128), dim3(512), 0, stream,
                     sc_ws, prev, enc, WkT, bk, q_ws, va, bsc, aligno, rnn_in);
  hipLaunchKernelGGL(zgemm_mfma_kernel, dim3(128, 4), dim3(256), 0, stream,
                     rnn_in, (const __bf16*)nullptr, 768, Wx1,
                     h1, h1bf, 1024, Wh1, parts);
  hipLaunchKernelGGL(gate_kernel, dim3(512), dim3(256), 0, stream,
                     parts, bl1, c1, h1n, c1n, h1nbf);
  hipLaunchKernelGGL(zgemm_mfma_kernel, dim3(128, 4), dim3(256), 0, stream,
                     h1n, h1nbf, 1024, Wx2,
                     h2, h2bf, 1024, Wh2, parts);
  hipLaunchKernelGGL(gateproj_kernel, dim3(128), dim3(1024), 0, stream,
                     parts, bl2, c2, rnn_in, Wpj, bpj, h2n, c2n, mel, stops);
}